// Round 4
// baseline (2131.595 us; speedup 1.0000x reference)
//
#include <hip/hip_runtime.h>

// ---------------- bf16 helpers (only for optional compact internal storage) ----------------
__device__ __forceinline__ float bf2f(unsigned short u) {
    union { unsigned int i; float f; } v;
    v.i = ((unsigned int)u) << 16;
    return v.f;
}
__device__ __forceinline__ unsigned short f2bf(float f) {
    union { float f; unsigned int i; } v;
    v.f = f;
    unsigned int lsb = (v.i >> 16) & 1u;
    v.i += 0x7fffu + lsb;   // round-to-nearest-even
    return (unsigned short)(v.i >> 16);
}

// typed 4-wide load/store (float or bf16 storage) -> fp32 math
__device__ __forceinline__ float4 ld4(const float* p) { return *(const float4*)p; }
__device__ __forceinline__ float4 ld4(const unsigned short* p) {
    ushort4 u = *(const ushort4*)p;
    float4 r; r.x = bf2f(u.x); r.y = bf2f(u.y); r.z = bf2f(u.z); r.w = bf2f(u.w);
    return r;
}
__device__ __forceinline__ void st4(float* p, float4 v) { *(float4*)p = v; }
__device__ __forceinline__ void st4(unsigned short* p, float4 v) {
    ushort4 u; u.x = f2bf(v.x); u.y = f2bf(v.y); u.z = f2bf(v.z); u.w = f2bf(v.w);
    *(ushort4*)p = u;
}
// per-lane feature-pair load/store (row-major rows of 128)
__device__ __forceinline__ float2 ld2pair(const float* rowp, int lane) {
    return ((const float2*)rowp)[lane];
}
__device__ __forceinline__ float2 ld2pair(const unsigned short* rowp, int lane) {
    unsigned int u = ((const unsigned int*)rowp)[lane];
    float2 r; r.x = bf2f((unsigned short)(u & 0xffffu));
    r.y = bf2f((unsigned short)(u >> 16));
    return r;
}
__device__ __forceinline__ void st2pair(float* rowp, int lane, float2 v) {
    ((float2*)rowp)[lane] = v;
}
__device__ __forceinline__ void st2pair(unsigned short* rowp, int lane, float2 v) {
    unsigned int u = (unsigned int)f2bf(v.x) | ((unsigned int)f2bf(v.y) << 16);
    ((unsigned int*)rowp)[lane] = u;
}
__device__ __forceinline__ float toF(float v) { return v; }
__device__ __forceinline__ float toF(unsigned short v) { return bf2f(v); }

#define HID 128   // feature width (D == H == 128)

// ---------------- preprocessing ----------------
__global__ void k_deg(const int* __restrict__ col, int* __restrict__ degI, int E) {
    int i = blockIdx.x * blockDim.x + threadIdx.x;
    if (i < E) atomicAdd(&degI[col[i]], 1);
}

__global__ void k_dinv(const int* __restrict__ degI, float* __restrict__ dinv, int N) {
    int i = blockIdx.x * blockDim.x + threadIdx.x;
    if (i < N) dinv[i] = 1.0f / sqrtf((float)(degI[i] + 1));  // +1 self loop
}

// single-block exclusive scan of (degI[i]+1) -> indptr (and cursor copy)
__global__ void k_scan_indptr(const int* __restrict__ degI, int* __restrict__ indptr,
                              int* __restrict__ cursor, int N) {
    __shared__ int sh[1024];
    __shared__ int carry;
    int tid = threadIdx.x;
    if (tid == 0) carry = 0;
    __syncthreads();
    for (int base = 0; base < N; base += 1024) {
        int i = base + tid;
        int v = (i < N) ? (degI[i] + 1) : 0;
        sh[tid] = v;
        __syncthreads();
        for (int off = 1; off < 1024; off <<= 1) {
            int t = (tid >= off) ? sh[tid - off] : 0;
            __syncthreads();
            sh[tid] += t;
            __syncthreads();
        }
        int cbase = carry;
        if (i < N) {
            int ex = cbase + sh[tid] - v;
            indptr[i] = ex;
            cursor[i] = ex;
        }
        __syncthreads();
        if (tid == 0) carry = cbase + sh[1023];
        __syncthreads();
    }
    if (threadIdx.x == 0) indptr[N] = carry;
}

// scatter edges (and self loops) into CSR-by-destination
__global__ void k_scatter(const int* __restrict__ row, const int* __restrict__ col,
                          const float* __restrict__ dinv, int* __restrict__ cursor,
                          int* __restrict__ srcs, float* __restrict__ enorm,
                          int E, int N) {
    int e = blockIdx.x * blockDim.x + threadIdx.x;
    if (e >= E + N) return;
    int s, d;
    if (e < E) { s = row[e]; d = col[e]; }
    else       { s = d = e - E; }          // self loop
    int p = atomicAdd(&cursor[d], 1);
    srcs[p]  = s;
    enorm[p] = dinv[s] * dinv[d];
}

__global__ void k_ghist(const int* __restrict__ batch, int* __restrict__ cntG, int N) {
    int i = blockIdx.x * blockDim.x + threadIdx.x;
    if (i < N) atomicAdd(&cntG[batch[i]], 1);
}

// single-block (512 threads) exclusive scan of graph counts (G <= 512)
__global__ void k_gscan(const int* __restrict__ cntG, int* __restrict__ gstart, int G) {
    __shared__ int sh[512];
    int tid = threadIdx.x;
    int v = (tid < G) ? cntG[tid] : 0;
    sh[tid] = v;
    __syncthreads();
    for (int off = 1; off < 512; off <<= 1) {
        int t = (tid >= off) ? sh[tid - off] : 0;
        __syncthreads();
        sh[tid] += t;
        __syncthreads();
    }
    if (tid < G) gstart[tid] = sh[tid] - v;
    if (tid == 511) gstart[G] = sh[511];
}

// ---------------- GEMM: C[N,128] = A[N,128] @ W[128,128] (all f32 math) -------
// block tile 128x128, 256 threads, 8x8 per thread, K chunked by 32 via LDS.
template <typename TA, typename TC>
__global__ __launch_bounds__(256, 2) void k_gemm128(const TA* __restrict__ Ap,
                                                    const float* __restrict__ Wb,
                                                    TC* __restrict__ C, int N) {
    __shared__ float As[32][132];  // k-major (transposed), +4 pad
    __shared__ float Ws[32][128];
    const int tid = threadIdx.x;
    const int tr = tid >> 4;   // 0..15 -> rows tr*8..+7
    const int tc = tid & 15;   // 0..15 -> cols tc*4..+3 and 64+tc*4..+3
    const int rowBase = blockIdx.x * 128;

    float acc[8][8];
#pragma unroll
    for (int i = 0; i < 8; ++i)
#pragma unroll
        for (int j = 0; j < 8; ++j) acc[i][j] = 0.f;

    for (int kb = 0; kb < 128; kb += 32) {
        // stage A chunk (128 rows x 32 k), transposed into As[k][r]
#pragma unroll
        for (int i = 0; i < 4; ++i) {
            int f4 = tid + i * 256;      // 0..1023
            int r  = f4 >> 3;            // 0..127
            int kc = (f4 & 7) << 2;      // 0,4,...,28
            int gr = rowBase + r;
            float4 v = {0.f, 0.f, 0.f, 0.f};
            if (gr < N) v = ld4(Ap + (size_t)gr * HID + kb + kc);
            As[kc + 0][r] = v.x; As[kc + 1][r] = v.y;
            As[kc + 2][r] = v.z; As[kc + 3][r] = v.w;
        }
        // stage W chunk (32 k x 128 cols)
#pragma unroll
        for (int i = 0; i < 4; ++i) {
            int f4 = tid + i * 256;
            int k  = f4 >> 5;            // 0..31
            int c4 = (f4 & 31) << 2;     // 0..124
            float4 wv = ld4(Wb + (size_t)(kb + k) * HID + c4);
            *(float4*)&Ws[k][c4] = wv;
        }
        __syncthreads();
#pragma unroll
        for (int k = 0; k < 32; ++k) {
            float a[8], w[8];
            *(float4*)&a[0] = *(const float4*)&As[k][tr * 8];
            *(float4*)&a[4] = *(const float4*)&As[k][tr * 8 + 4];
            *(float4*)&w[0] = *(const float4*)&Ws[k][tc * 4];
            *(float4*)&w[4] = *(const float4*)&Ws[k][64 + tc * 4];
#pragma unroll
            for (int i = 0; i < 8; ++i)
#pragma unroll
                for (int j = 0; j < 8; ++j)
                    acc[i][j] = fmaf(a[i], w[j], acc[i][j]);
        }
        __syncthreads();
    }
#pragma unroll
    for (int i = 0; i < 8; ++i) {
        int gr = rowBase + tr * 8 + i;
        if (gr < N) {
            float4 o0 = {acc[i][0], acc[i][1], acc[i][2], acc[i][3]};
            float4 o1 = {acc[i][4], acc[i][5], acc[i][6], acc[i][7]};
            st4(C + (size_t)gr * HID + tc * 4, o0);
            st4(C + (size_t)gr * HID + 64 + tc * 4, o1);
        }
    }
}

// ---------------- CSR gather-aggregate + bias + ReLU ----------------
// one wave (64 lanes) per destination node; 2 feats per lane
template <typename TS>
__global__ __launch_bounds__(256) void k_aggregate(const TS* __restrict__ t,
                                                   const int* __restrict__ indptr,
                                                   const int* __restrict__ srcs,
                                                   const float* __restrict__ enorm,
                                                   const float* __restrict__ bias,
                                                   TS* __restrict__ h, int N) {
    int node = blockIdx.x * 4 + (threadIdx.x >> 6);
    if (node >= N) return;
    int lane = threadIdx.x & 63;
    int s = indptr[node], e = indptr[node + 1];
    float ax = 0.f, ay = 0.f, bx = 0.f, by = 0.f;
    int p = s;
    for (; p + 1 < e; p += 2) {
        int   s0 = srcs[p],  s1 = srcs[p + 1];
        float w0 = enorm[p], w1 = enorm[p + 1];
        float2 v0 = ld2pair(t + (size_t)s0 * HID, lane);
        float2 v1 = ld2pair(t + (size_t)s1 * HID, lane);
        ax = fmaf(w0, v0.x, ax); ay = fmaf(w0, v0.y, ay);
        bx = fmaf(w1, v1.x, bx); by = fmaf(w1, v1.y, by);
    }
    if (p < e) {
        int s0 = srcs[p]; float w0 = enorm[p];
        float2 v0 = ld2pair(t + (size_t)s0 * HID, lane);
        ax = fmaf(w0, v0.x, ax); ay = fmaf(w0, v0.y, ay);
    }
    float2 o;
    o.x = fmaxf(ax + bx + bias[lane * 2], 0.f);
    o.y = fmaxf(ay + by + bias[lane * 2 + 1], 0.f);
    st2pair(h + (size_t)node * HID, lane, o);
}

// ---------------- segment mean-pool (batch is sorted) ----------------
template <typename TS>
__global__ void k_pool(const TS* __restrict__ h, const int* __restrict__ gstart,
                       const int* __restrict__ cntG, float* __restrict__ pbuf, int layer) {
    int g = blockIdx.x;
    int c = threadIdx.x;  // 128 threads
    int s = gstart[g], e = gstart[g + 1];
    float sum = 0.f;
    for (int v = s; v < e; ++v) sum += toF(h[(size_t)v * HID + c]);
    float cnt = (float)cntG[g];
    pbuf[(size_t)g * 640 + layer * HID + c] = sum / fmaxf(cnt, 1.0f);
}

// ---------------- MLP head (f32 weights) ----------------
__global__ void k_fc1(const float* __restrict__ pbuf, const float* __restrict__ Wl1,
                      const float* __restrict__ bl1, float* __restrict__ zbuf) {
    __shared__ float psh[640];
    int g = blockIdx.x;
    for (int k = threadIdx.x; k < 640; k += 256) psh[k] = pbuf[(size_t)g * 640 + k];
    __syncthreads();
    int j0 = threadIdx.x, j1 = j0 + 256, j2 = j0 + 512;
    float a0 = 0.f, a1 = 0.f, a2 = 0.f;
    for (int k = 0; k < 640; ++k) {
        float pv = psh[k];
        const float* wr = Wl1 + (size_t)k * 640;
        a0 = fmaf(pv, wr[j0], a0);
        a1 = fmaf(pv, wr[j1], a1);
        if (j2 < 640) a2 = fmaf(pv, wr[j2], a2);
    }
    zbuf[(size_t)g * 640 + j0] = fmaxf(a0 + bl1[j0], 0.f);
    zbuf[(size_t)g * 640 + j1] = fmaxf(a1 + bl1[j1], 0.f);
    if (j2 < 640) zbuf[(size_t)g * 640 + j2] = fmaxf(a2 + bl1[j2], 0.f);
}

__global__ void k_fc2(const float* __restrict__ zbuf, const float* __restrict__ Wl2,
                      const float* __restrict__ bl2, float* __restrict__ out) {
    int g = blockIdx.x;
    int t = threadIdx.x;  // 128 threads = 2 waves
    float s = 0.f;
    for (int k = t; k < 640; k += 128) s = fmaf(zbuf[(size_t)g * 640 + k], Wl2[k], s);
#pragma unroll
    for (int off = 32; off > 0; off >>= 1) s += __shfl_down(s, off);
    __shared__ float ws[2];
    if ((t & 63) == 0) ws[t >> 6] = s;
    __syncthreads();
    if (t == 0) out[g] = ws[0] + ws[1] + bl2[0];
}

// ---------------- typed pipeline driver ----------------
template <typename TS>
static void run_layers(const float* x, const float* const* Ws_,
                       const float* const* bs_, TS* buf0, TS* buf1,
                       const int* indptr, const int* srcs, const float* enorm,
                       const int* gstart, const int* cntG, float* pbuf,
                       int N, int G, hipStream_t stream) {
    const int gemmGrid = (N + 127) / 128;
    const int aggGrid  = (N + 3) / 4;
    for (int L = 0; L < 5; ++L) {
        if (L == 0)
            k_gemm128<float, TS><<<gemmGrid, 256, 0, stream>>>(x, Ws_[0], buf0, N);
        else
            k_gemm128<TS, TS><<<gemmGrid, 256, 0, stream>>>(buf1, Ws_[L], buf0, N);
        k_aggregate<TS><<<aggGrid, 256, 0, stream>>>(buf0, indptr, srcs, enorm, bs_[L], buf1, N);
        k_pool<TS><<<G, 128, 0, stream>>>(buf1, gstart, cntG, pbuf, L);
    }
}

extern "C" void kernel_launch(void* const* d_in, const int* in_sizes, int n_in,
                              void* d_out, int out_size, void* d_ws, size_t ws_size,
                              hipStream_t stream) {
    // All float tensors are float32 per the reference (setup_inputs uses
    // jnp.float32 everywhere); indices are int32. Output is float32.
    const float* x    = (const float*)d_in[0];
    const int*   edge = (const int*)d_in[1];
    const int*   bat  = (const int*)d_in[2];
    const float* W1   = (const float*)d_in[3];
    const float* b1   = (const float*)d_in[4];
    const float* W2   = (const float*)d_in[5];
    const float* b2   = (const float*)d_in[6];
    const float* W3   = (const float*)d_in[7];
    const float* b3   = (const float*)d_in[8];
    const float* W4   = (const float*)d_in[9];
    const float* b4   = (const float*)d_in[10];
    const float* Wl1  = (const float*)d_in[11];
    const float* bl1  = (const float*)d_in[12];
    const float* Wl2  = (const float*)d_in[13];
    const float* bl2  = (const float*)d_in[14];
    float*       out  = (float*)d_out;

    const int N = in_sizes[2];       // 100000
    const int E = in_sizes[1] / 2;   // 1600000
    const int G = out_size;          // 512
    (void)n_in;

    (void)hipGetLastError();  // clear any stale error

    // ---- workspace budget check ----
    auto al = [](size_t b) -> size_t { return (b + 255) & ~(size_t)255; };
    const size_t miscBytes =
        al((size_t)N * 4) * 3 +            // dinv, degI, cursor
        al((size_t)(N + 1) * 4) +          // indptr
        al((size_t)(E + N) * 4) * 2 +      // srcs, enorm
        al((size_t)G * 4) + al((size_t)(G + 1) * 4) +  // cntG, gstart
        al((size_t)G * 640 * 4) * 2;       // pbuf, zbuf
    const size_t needF32 = miscBytes + 2 * al((size_t)N * HID * 4);
    const size_t needB16 = miscBytes + 2 * al((size_t)N * HID * 2);
    const bool  wsUnknown = (ws_size == 0);
    const bool  useF32 = wsUnknown || ws_size >= needF32;
    if (!useF32 && ws_size < needB16) {
        // sentinel: workspace too small even for bf16 plan (absmax ~= 12)
        hipMemsetAsync(d_out, 0x41, (size_t)out_size * 4, stream);
        return;
    }

    // ---- workspace carve ----
    size_t off = 0;
    auto alloc = [&](size_t bytes) -> void* {
        void* p = (void*)((char*)d_ws + off);
        off += al(bytes);
        return p;
    };
    const size_t es = useF32 ? 4 : 2;
    void*  buf0v  = alloc((size_t)N * HID * es);
    void*  buf1v  = alloc((size_t)N * HID * es);
    float* dinv   = (float*)alloc((size_t)N * 4);
    int*   degI   = (int*)alloc((size_t)N * 4);
    int*   cursor = (int*)alloc((size_t)N * 4);
    int*   indptr = (int*)alloc((size_t)(N + 1) * 4);
    int*   srcs   = (int*)alloc((size_t)(E + N) * 4);
    float* enorm  = (float*)alloc((size_t)(E + N) * 4);
    int*   cntG   = (int*)alloc((size_t)G * 4);
    int*   gstart = (int*)alloc((size_t)(G + 1) * 4);
    float* pbuf   = (float*)alloc((size_t)G * 640 * 4);
    float* zbuf   = (float*)alloc((size_t)G * 640 * 4);

    const int* rowv = edge;      // sources
    const int* colv = edge + E;  // destinations

    // ---- preprocessing (once, reused by all 5 convs) ----
    hipMemsetAsync(degI, 0, (size_t)N * 4, stream);
    hipMemsetAsync(cntG, 0, (size_t)G * 4, stream);
    k_deg<<<(E + 255) / 256, 256, 0, stream>>>(colv, degI, E);
    k_dinv<<<(N + 255) / 256, 256, 0, stream>>>(degI, dinv, N);
    k_scan_indptr<<<1, 1024, 0, stream>>>(degI, indptr, cursor, N);
    k_scatter<<<(E + N + 255) / 256, 256, 0, stream>>>(rowv, colv, dinv, cursor,
                                                       srcs, enorm, E, N);
    k_ghist<<<(N + 255) / 256, 256, 0, stream>>>(bat, cntG, N);
    k_gscan<<<1, 512, 0, stream>>>(cntG, gstart, G);

    // ---- 5 GCN layers (layer 5 reuses W4/b4, matching the reference) ----
    const float* Ws_[5] = {W1, W2, W3, W4, W4};
    const float* bs_[5] = {b1, b2, b3, b4, b4};
    if (useF32)
        run_layers<float>(x, Ws_, bs_, (float*)buf0v, (float*)buf1v,
                          indptr, srcs, enorm, gstart, cntG, pbuf, N, G, stream);
    else
        run_layers<unsigned short>(x, Ws_, bs_, (unsigned short*)buf0v,
                                   (unsigned short*)buf1v,
                                   indptr, srcs, enorm, gstart, cntG, pbuf, N, G, stream);

    // ---- MLP head ----
    k_fc1<<<G, 256, 0, stream>>>(pbuf, Wl1, bl1, zbuf);
    k_fc2<<<G, 128, 0, stream>>>(zbuf, Wl2, bl2, out);

    // sentinel: some launch failed synchronously (absmax ~= 48)
    if (hipGetLastError() != hipSuccess)
        hipMemsetAsync(d_out, 0x42, (size_t)out_size * 4, stream);
}

// Round 5
// 1587.185 us; speedup vs baseline: 1.3430x; 1.3430x over previous
//
#include <hip/hip_runtime.h>

#define HID 128   // feature width (D == H == 128)

// ---------------- preprocessing ----------------
__global__ void k_deg(const int* __restrict__ col, int* __restrict__ degI, int E) {
    int i = blockIdx.x * blockDim.x + threadIdx.x;
    if (i < E) atomicAdd(&degI[col[i]], 1);
}

__global__ void k_dinv(const int* __restrict__ degI, float* __restrict__ dinv, int N) {
    int i = blockIdx.x * blockDim.x + threadIdx.x;
    if (i < N) dinv[i] = 1.0f / sqrtf((float)(degI[i] + 1));  // +1 self loop
}

// ---- 3-phase device-wide exclusive scan of (degI[i]+1) -> indptr, cursor ----
// phase 1: per-block (1024 elems) exclusive scan + block total
__global__ void k_scan_part(const int* __restrict__ degI, int* __restrict__ partial,
                            int* __restrict__ sums, int N) {
    __shared__ int sh[1024];
    int tid = threadIdx.x;
    int i = blockIdx.x * 1024 + tid;
    int v = (i < N) ? (degI[i] + 1) : 0;
    sh[tid] = v;
    __syncthreads();
    for (int off = 1; off < 1024; off <<= 1) {
        int t = (tid >= off) ? sh[tid - off] : 0;
        __syncthreads();
        sh[tid] += t;
        __syncthreads();
    }
    if (i < N) partial[i] = sh[tid] - v;
    if (tid == 1023) sums[blockIdx.x] = sh[1023];
}
// phase 2: single block scans the block totals (nblocks <= 1024), writes grand total
__global__ void k_scan_tops(int* __restrict__ sums, int* __restrict__ indptr,
                            int nblocks, int N) {
    __shared__ int sh[1024];
    int tid = threadIdx.x;
    int v = (tid < nblocks) ? sums[tid] : 0;
    sh[tid] = v;
    __syncthreads();
    for (int off = 1; off < 1024; off <<= 1) {
        int t = (tid >= off) ? sh[tid - off] : 0;
        __syncthreads();
        sh[tid] += t;
        __syncthreads();
    }
    if (tid < nblocks) sums[tid] = sh[tid] - v;   // exclusive
    if (tid == 1023) indptr[N] = sh[1023];        // grand total = E + N
}
// phase 3: add block offsets, emit indptr + cursor copy
__global__ void k_scan_fix(const int* __restrict__ partial, const int* __restrict__ sums,
                           int* __restrict__ indptr, int* __restrict__ cursor, int N) {
    int i = blockIdx.x * blockDim.x + threadIdx.x;
    if (i < N) {
        int ex = partial[i] + sums[i >> 10];
        indptr[i] = ex;
        cursor[i] = ex;
    }
}

// scatter edges (and self loops) into CSR-by-destination
__global__ void k_scatter(const int* __restrict__ row, const int* __restrict__ col,
                          const float* __restrict__ dinv, int* __restrict__ cursor,
                          int* __restrict__ srcs, float* __restrict__ enorm,
                          int E, int N) {
    int e = blockIdx.x * blockDim.x + threadIdx.x;
    if (e >= E + N) return;
    int s, d;
    if (e < E) { s = row[e]; d = col[e]; }
    else       { s = d = e - E; }          // self loop
    int p = atomicAdd(&cursor[d], 1);
    srcs[p]  = s;
    enorm[p] = dinv[s] * dinv[d];
}

__global__ void k_ghist(const int* __restrict__ batch, int* __restrict__ cntG, int N) {
    int i = blockIdx.x * blockDim.x + threadIdx.x;
    if (i < N) atomicAdd(&cntG[batch[i]], 1);
}

// single-block (512 threads) exclusive scan of graph counts (G <= 512)
__global__ void k_gscan(const int* __restrict__ cntG, int* __restrict__ gstart, int G) {
    __shared__ int sh[512];
    int tid = threadIdx.x;
    int v = (tid < G) ? cntG[tid] : 0;
    sh[tid] = v;
    __syncthreads();
    for (int off = 1; off < 512; off <<= 1) {
        int t = (tid >= off) ? sh[tid - off] : 0;
        __syncthreads();
        sh[tid] += t;
        __syncthreads();
    }
    if (tid < G) gstart[tid] = sh[tid] - v;
    if (tid == 511) gstart[G] = sh[511];
}

// ---------------- GEMM: C[N,128] = A[N,128] @ W[128,128] (f32) ---------------
// block tile 128x128, 256 threads, 8x8 per thread, K chunked by 32 via LDS.
__global__ __launch_bounds__(256, 2) void k_gemm128(const float* __restrict__ Ap,
                                                    const float* __restrict__ Wb,
                                                    float* __restrict__ C, int N) {
    __shared__ float As[32][132];  // k-major (transposed), +4 pad
    __shared__ float Ws[32][128];
    const int tid = threadIdx.x;
    const int tr = tid >> 4;   // 0..15 -> rows tr*8..+7
    const int tc = tid & 15;   // 0..15 -> cols tc*4..+3 and 64+tc*4..+3
    const int rowBase = blockIdx.x * 128;

    float acc[8][8];
#pragma unroll
    for (int i = 0; i < 8; ++i)
#pragma unroll
        for (int j = 0; j < 8; ++j) acc[i][j] = 0.f;

    for (int kb = 0; kb < 128; kb += 32) {
#pragma unroll
        for (int i = 0; i < 4; ++i) {
            int f4 = tid + i * 256;      // 0..1023
            int r  = f4 >> 3;            // 0..127
            int kc = (f4 & 7) << 2;      // 0,4,...,28
            int gr = rowBase + r;
            float4 v = {0.f, 0.f, 0.f, 0.f};
            if (gr < N) v = *(const float4*)(Ap + (size_t)gr * HID + kb + kc);
            As[kc + 0][r] = v.x; As[kc + 1][r] = v.y;
            As[kc + 2][r] = v.z; As[kc + 3][r] = v.w;
        }
#pragma unroll
        for (int i = 0; i < 4; ++i) {
            int f4 = tid + i * 256;
            int k  = f4 >> 5;            // 0..31
            int c4 = (f4 & 31) << 2;     // 0..124
            *(float4*)&Ws[k][c4] = *(const float4*)(Wb + (size_t)(kb + k) * HID + c4);
        }
        __syncthreads();
#pragma unroll
        for (int k = 0; k < 32; ++k) {
            float a[8], w[8];
            *(float4*)&a[0] = *(const float4*)&As[k][tr * 8];
            *(float4*)&a[4] = *(const float4*)&As[k][tr * 8 + 4];
            *(float4*)&w[0] = *(const float4*)&Ws[k][tc * 4];
            *(float4*)&w[4] = *(const float4*)&Ws[k][64 + tc * 4];
#pragma unroll
            for (int i = 0; i < 8; ++i)
#pragma unroll
                for (int j = 0; j < 8; ++j)
                    acc[i][j] = fmaf(a[i], w[j], acc[i][j]);
        }
        __syncthreads();
    }
#pragma unroll
    for (int i = 0; i < 8; ++i) {
        int gr = rowBase + tr * 8 + i;
        if (gr < N) {
            float4 o0 = {acc[i][0], acc[i][1], acc[i][2], acc[i][3]};
            float4 o1 = {acc[i][4], acc[i][5], acc[i][6], acc[i][7]};
            *(float4*)(C + (size_t)gr * HID + tc * 4) = o0;
            *(float4*)(C + (size_t)gr * HID + 64 + tc * 4) = o1;
        }
    }
}

// ---------------- CSR gather-aggregate + bias + ReLU ----------------
// one wave (64 lanes) per destination node; 2 feats per lane; 4 edges in flight
__global__ __launch_bounds__(256) void k_aggregate(const float* __restrict__ t,
                                                   const int* __restrict__ indptr,
                                                   const int* __restrict__ srcs,
                                                   const float* __restrict__ enorm,
                                                   const float* __restrict__ bias,
                                                   float* __restrict__ h, int N) {
    int node = blockIdx.x * 4 + (threadIdx.x >> 6);
    if (node >= N) return;
    int lane = threadIdx.x & 63;
    int s = indptr[node], e = indptr[node + 1];
    float a0x = 0.f, a0y = 0.f, a1x = 0.f, a1y = 0.f;
    float a2x = 0.f, a2y = 0.f, a3x = 0.f, a3y = 0.f;
    int p = s;
    for (; p + 3 < e; p += 4) {
        int   s0 = srcs[p],     s1 = srcs[p + 1], s2 = srcs[p + 2], s3 = srcs[p + 3];
        float w0 = enorm[p],    w1 = enorm[p + 1];
        float w2 = enorm[p + 2], w3 = enorm[p + 3];
        float2 v0 = ((const float2*)(t + (size_t)s0 * HID))[lane];
        float2 v1 = ((const float2*)(t + (size_t)s1 * HID))[lane];
        float2 v2 = ((const float2*)(t + (size_t)s2 * HID))[lane];
        float2 v3 = ((const float2*)(t + (size_t)s3 * HID))[lane];
        a0x = fmaf(w0, v0.x, a0x); a0y = fmaf(w0, v0.y, a0y);
        a1x = fmaf(w1, v1.x, a1x); a1y = fmaf(w1, v1.y, a1y);
        a2x = fmaf(w2, v2.x, a2x); a2y = fmaf(w2, v2.y, a2y);
        a3x = fmaf(w3, v3.x, a3x); a3y = fmaf(w3, v3.y, a3y);
    }
    for (; p < e; ++p) {
        int s0 = srcs[p]; float w0 = enorm[p];
        float2 v0 = ((const float2*)(t + (size_t)s0 * HID))[lane];
        a0x = fmaf(w0, v0.x, a0x); a0y = fmaf(w0, v0.y, a0y);
    }
    float2 o;
    o.x = fmaxf((a0x + a1x) + (a2x + a3x) + bias[lane * 2], 0.f);
    o.y = fmaxf((a0y + a1y) + (a2y + a3y) + bias[lane * 2 + 1], 0.f);
    ((float2*)(h + (size_t)node * HID))[lane] = o;
}

// ---------------- segment mean-pool (batch is sorted) ----------------
__global__ void k_pool(const float* __restrict__ h, const int* __restrict__ gstart,
                       const int* __restrict__ cntG, float* __restrict__ pbuf, int layer) {
    int g = blockIdx.x;
    int c = threadIdx.x;  // 128 threads
    int s = gstart[g], e = gstart[g + 1];
    float sum = 0.f;
    for (int v = s; v < e; ++v) sum += h[(size_t)v * HID + c];
    float cnt = (float)cntG[g];
    pbuf[(size_t)g * 640 + layer * HID + c] = sum / fmaxf(cnt, 1.0f);
}

// ---------------- MLP head: Z[G,640] = relu(P[G,640] @ Wl1 + bl1) ------------
// tiled GEMM: 64x64 tile per block, 256 threads, 4x4 per thread, K chunked by 64
__global__ __launch_bounds__(256) void k_head1(const float* __restrict__ P,
                                               const float* __restrict__ Wl1,
                                               const float* __restrict__ bl1,
                                               float* __restrict__ Z, int G) {
    __shared__ float As[64][68];   // k-major: As[k][g], pad to 68
    __shared__ float Ws[64][64];   // Ws[k][c]
    const int tid = threadIdx.x;
    const int tr = tid >> 4;       // 0..15 -> local rows tr*4..+3
    const int tc = tid & 15;       // 0..15 -> local cols tc*4..+3
    const int gBase = blockIdx.x * 64;   // graph-tile origin
    const int cBase = blockIdx.y * 64;   // output-col tile origin

    float acc[4][4];
#pragma unroll
    for (int i = 0; i < 4; ++i)
#pragma unroll
        for (int j = 0; j < 4; ++j) acc[i][j] = 0.f;

    for (int kb = 0; kb < 640; kb += 64) {
        // stage P tile: 64 graphs x 64 k, transposed
#pragma unroll
        for (int i = 0; i < 4; ++i) {
            int f4 = tid + i * 256;        // 0..1023
            int r  = f4 >> 4;              // 0..63 (local graph)
            int kc = (f4 & 15) << 2;       // 0..60
            int gg = gBase + r;
            float4 v = {0.f, 0.f, 0.f, 0.f};
            if (gg < G) v = *(const float4*)(P + (size_t)gg * 640 + kb + kc);
            As[kc + 0][r] = v.x; As[kc + 1][r] = v.y;
            As[kc + 2][r] = v.z; As[kc + 3][r] = v.w;
        }
        // stage W tile: 64 k x 64 cols
#pragma unroll
        for (int i = 0; i < 4; ++i) {
            int f4 = tid + i * 256;
            int k  = f4 >> 4;              // 0..63
            int c4 = (f4 & 15) << 2;       // 0..60
            *(float4*)&Ws[k][c4] =
                *(const float4*)(Wl1 + (size_t)(kb + k) * 640 + cBase + c4);
        }
        __syncthreads();
#pragma unroll
        for (int k = 0; k < 64; ++k) {
            float a[4], w[4];
            *(float4*)&a[0] = *(const float4*)&As[k][tr * 4];
            *(float4*)&w[0] = *(const float4*)&Ws[k][tc * 4];
#pragma unroll
            for (int i = 0; i < 4; ++i)
#pragma unroll
                for (int j = 0; j < 4; ++j)
                    acc[i][j] = fmaf(a[i], w[j], acc[i][j]);
        }
        __syncthreads();
    }
#pragma unroll
    for (int i = 0; i < 4; ++i) {
        int gg = gBase + tr * 4 + i;
        if (gg < G) {
            float4 o;
            o.x = fmaxf(acc[i][0] + bl1[cBase + tc * 4 + 0], 0.f);
            o.y = fmaxf(acc[i][1] + bl1[cBase + tc * 4 + 1], 0.f);
            o.z = fmaxf(acc[i][2] + bl1[cBase + tc * 4 + 2], 0.f);
            o.w = fmaxf(acc[i][3] + bl1[cBase + tc * 4 + 3], 0.f);
            *(float4*)(Z + (size_t)gg * 640 + cBase + tc * 4) = o;
        }
    }
}

__global__ void k_fc2(const float* __restrict__ zbuf, const float* __restrict__ Wl2,
                      const float* __restrict__ bl2, float* __restrict__ out) {
    int g = blockIdx.x;
    int t = threadIdx.x;  // 128 threads = 2 waves
    float s = 0.f;
    for (int k = t; k < 640; k += 128) s = fmaf(zbuf[(size_t)g * 640 + k], Wl2[k], s);
#pragma unroll
    for (int off = 32; off > 0; off >>= 1) s += __shfl_down(s, off);
    __shared__ float ws[2];
    if ((t & 63) == 0) ws[t >> 6] = s;
    __syncthreads();
    if (t == 0) out[g] = ws[0] + ws[1] + bl2[0];
}

// ---------------- driver ----------------
extern "C" void kernel_launch(void* const* d_in, const int* in_sizes, int n_in,
                              void* d_out, int out_size, void* d_ws, size_t ws_size,
                              hipStream_t stream) {
    // All float tensors are float32 (reference setup_inputs); indices int32.
    const float* x    = (const float*)d_in[0];
    const int*   edge = (const int*)d_in[1];
    const int*   bat  = (const int*)d_in[2];
    const float* W1   = (const float*)d_in[3];
    const float* b1   = (const float*)d_in[4];
    const float* W2   = (const float*)d_in[5];
    const float* b2   = (const float*)d_in[6];
    const float* W3   = (const float*)d_in[7];
    const float* b3   = (const float*)d_in[8];
    const float* W4   = (const float*)d_in[9];
    const float* b4   = (const float*)d_in[10];
    const float* Wl1  = (const float*)d_in[11];
    const float* bl1  = (const float*)d_in[12];
    const float* Wl2  = (const float*)d_in[13];
    const float* bl2  = (const float*)d_in[14];
    float*       out  = (float*)d_out;

    const int N = in_sizes[2];       // 100000
    const int E = in_sizes[1] / 2;   // 1600000
    const int G = out_size;          // 512
    (void)n_in; (void)ws_size;

    (void)hipGetLastError();  // clear any stale error

    // ---- workspace carve (~119 MB; ws verified sufficient in round 4) ----
    size_t off = 0;
    auto alloc = [&](size_t bytes) -> void* {
        void* p = (void*)((char*)d_ws + off);
        off += (bytes + 255) & ~(size_t)255;
        return p;
    };
    float* buf0   = (float*)alloc((size_t)N * HID * 4);
    float* buf1   = (float*)alloc((size_t)N * HID * 4);
    float* dinv   = (float*)alloc((size_t)N * 4);
    int*   degI   = (int*)alloc((size_t)N * 4);
    int*   cursor = (int*)alloc((size_t)N * 4);
    int*   indptr = (int*)alloc((size_t)(N + 1) * 4);
    int*   partial= (int*)alloc((size_t)N * 4);
    int*   bsums  = (int*)alloc((size_t)1024 * 4);
    int*   srcs   = (int*)alloc((size_t)(E + N) * 4);
    float* enorm  = (float*)alloc((size_t)(E + N) * 4);
    int*   cntG   = (int*)alloc((size_t)G * 4);
    int*   gstart = (int*)alloc((size_t)(G + 1) * 4);
    float* pbuf   = (float*)alloc((size_t)G * 640 * 4);
    float* zbuf   = (float*)alloc((size_t)G * 640 * 4);

    const int* rowv = edge;      // sources
    const int* colv = edge + E;  // destinations

    // ---- preprocessing (once, reused by all 5 convs) ----
    hipMemsetAsync(degI, 0, (size_t)N * 4, stream);
    hipMemsetAsync(cntG, 0, (size_t)G * 4, stream);
    k_deg<<<(E + 255) / 256, 256, 0, stream>>>(colv, degI, E);
    k_dinv<<<(N + 255) / 256, 256, 0, stream>>>(degI, dinv, N);
    const int scanBlocks = (N + 1023) / 1024;   // 98 <= 1024
    k_scan_part<<<scanBlocks, 1024, 0, stream>>>(degI, partial, bsums, N);
    k_scan_tops<<<1, 1024, 0, stream>>>(bsums, indptr, scanBlocks, N);
    k_scan_fix<<<(N + 255) / 256, 256, 0, stream>>>(partial, bsums, indptr, cursor, N);
    k_scatter<<<(E + N + 255) / 256, 256, 0, stream>>>(rowv, colv, dinv, cursor,
                                                       srcs, enorm, E, N);
    k_ghist<<<(N + 255) / 256, 256, 0, stream>>>(bat, cntG, N);
    k_gscan<<<1, 512, 0, stream>>>(cntG, gstart, G);

    // ---- 5 GCN layers (layer 5 reuses W4/b4, matching the reference) ----
    const float* Ws_[5] = {W1, W2, W3, W4, W4};
    const float* bs_[5] = {b1, b2, b3, b4, b4};
    const int gemmGrid = (N + 127) / 128;
    const int aggGrid  = (N + 3) / 4;
    for (int L = 0; L < 5; ++L) {
        const float* src = (L == 0) ? x : buf1;
        k_gemm128<<<gemmGrid, 256, 0, stream>>>(src, Ws_[L], buf0, N);
        k_aggregate<<<aggGrid, 256, 0, stream>>>(buf0, indptr, srcs, enorm, bs_[L], buf1, N);
        k_pool<<<G, 128, 0, stream>>>(buf1, gstart, cntG, pbuf, L);
    }

    // ---- MLP head ----
    dim3 hgrid((G + 63) / 64, 10);   // 640 output cols / 64
    k_head1<<<hgrid, 256, 0, stream>>>(pbuf, Wl1, bl1, zbuf, G);
    k_fc2<<<G, 128, 0, stream>>>(zbuf, Wl2, bl2, out);

    // sentinel: some launch failed synchronously (absmax ~= 48)
    if (hipGetLastError() != hipSuccess)
        hipMemsetAsync(d_out, 0x42, (size_t)out_size * 4, stream);
}

// Round 6
// 1391.079 us; speedup vs baseline: 1.5323x; 1.1410x over previous
//
#include <hip/hip_runtime.h>

#define HID 128   // feature width (D == H == 128)

// ---------------- bf16 helpers (internal storage of the gather table) --------
__device__ __forceinline__ float bf2f(unsigned short u) {
    union { unsigned int i; float f; } v;
    v.i = ((unsigned int)u) << 16;
    return v.f;
}
__device__ __forceinline__ unsigned short f2bf(float f) {
    union { float f; unsigned int i; } v;
    v.f = f;
    unsigned int lsb = (v.i >> 16) & 1u;
    v.i += 0x7fffu + lsb;   // round-to-nearest-even
    return (unsigned short)(v.i >> 16);
}

// ---------------- preprocessing ----------------
__global__ void k_deg(const int* __restrict__ col, int* __restrict__ degI, int E) {
    int i = blockIdx.x * blockDim.x + threadIdx.x;
    if (i < E) atomicAdd(&degI[col[i]], 1);
}

__global__ void k_dinv(const int* __restrict__ degI, float* __restrict__ dinv, int N) {
    int i = blockIdx.x * blockDim.x + threadIdx.x;
    if (i < N) dinv[i] = 1.0f / sqrtf((float)(degI[i] + 1));  // +1 self loop
}

// ---- 3-phase device-wide exclusive scan of (degI[i]+1) -> indptr, cursor ----
__global__ void k_scan_part(const int* __restrict__ degI, int* __restrict__ partial,
                            int* __restrict__ sums, int N) {
    __shared__ int sh[1024];
    int tid = threadIdx.x;
    int i = blockIdx.x * 1024 + tid;
    int v = (i < N) ? (degI[i] + 1) : 0;
    sh[tid] = v;
    __syncthreads();
    for (int off = 1; off < 1024; off <<= 1) {
        int t = (tid >= off) ? sh[tid - off] : 0;
        __syncthreads();
        sh[tid] += t;
        __syncthreads();
    }
    if (i < N) partial[i] = sh[tid] - v;
    if (tid == 1023) sums[blockIdx.x] = sh[1023];
}
__global__ void k_scan_tops(int* __restrict__ sums, int* __restrict__ indptr,
                            int nblocks, int N) {
    __shared__ int sh[1024];
    int tid = threadIdx.x;
    int v = (tid < nblocks) ? sums[tid] : 0;
    sh[tid] = v;
    __syncthreads();
    for (int off = 1; off < 1024; off <<= 1) {
        int t = (tid >= off) ? sh[tid - off] : 0;
        __syncthreads();
        sh[tid] += t;
        __syncthreads();
    }
    if (tid < nblocks) sums[tid] = sh[tid] - v;   // exclusive
    if (tid == 1023) indptr[N] = sh[1023];        // grand total = E + N
}
__global__ void k_scan_fix(const int* __restrict__ partial, const int* __restrict__ sums,
                           int* __restrict__ indptr, int* __restrict__ cursor, int N) {
    int i = blockIdx.x * blockDim.x + threadIdx.x;
    if (i < N) {
        int ex = partial[i] + sums[i >> 10];
        indptr[i] = ex;
        cursor[i] = ex;
    }
}

// scatter edges (and self loops) into CSR-by-destination
__global__ void k_scatter(const int* __restrict__ row, const int* __restrict__ col,
                          const float* __restrict__ dinv, int* __restrict__ cursor,
                          int* __restrict__ srcs, float* __restrict__ enorm,
                          int E, int N) {
    int e = blockIdx.x * blockDim.x + threadIdx.x;
    if (e >= E + N) return;
    int s, d;
    if (e < E) { s = row[e]; d = col[e]; }
    else       { s = d = e - E; }          // self loop
    int p = atomicAdd(&cursor[d], 1);
    srcs[p]  = s;
    enorm[p] = dinv[s] * dinv[d];
}

__global__ void k_ghist(const int* __restrict__ batch, int* __restrict__ cntG, int N) {
    int i = blockIdx.x * blockDim.x + threadIdx.x;
    if (i < N) atomicAdd(&cntG[batch[i]], 1);
}

__global__ void k_gscan(const int* __restrict__ cntG, int* __restrict__ gstart, int G) {
    __shared__ int sh[512];
    int tid = threadIdx.x;
    int v = (tid < G) ? cntG[tid] : 0;
    sh[tid] = v;
    __syncthreads();
    for (int off = 1; off < 512; off <<= 1) {
        int t = (tid >= off) ? sh[tid - off] : 0;
        __syncthreads();
        sh[tid] += t;
        __syncthreads();
    }
    if (tid < G) gstart[tid] = sh[tid] - v;
    if (tid == 511) gstart[G] = sh[511];
}

// ---------------- GEMM: T[N,128](bf16) = A[N,128](f32) @ W[128,128](f32) -----
// block tile 128x128, 256 threads, 8x8 per thread, K chunked by 32 via LDS.
// Epilogue stores bf16 — the aggregation gather table is half-width.
__global__ __launch_bounds__(256, 2) void k_gemm128(const float* __restrict__ Ap,
                                                    const float* __restrict__ Wb,
                                                    unsigned short* __restrict__ C, int N) {
    __shared__ float As[32][132];  // k-major (transposed), +4 pad
    __shared__ float Ws[32][128];
    const int tid = threadIdx.x;
    const int tr = tid >> 4;   // 0..15 -> rows tr*8..+7
    const int tc = tid & 15;   // 0..15 -> cols tc*4..+3 and 64+tc*4..+3
    const int rowBase = blockIdx.x * 128;

    float acc[8][8];
#pragma unroll
    for (int i = 0; i < 8; ++i)
#pragma unroll
        for (int j = 0; j < 8; ++j) acc[i][j] = 0.f;

    for (int kb = 0; kb < 128; kb += 32) {
#pragma unroll
        for (int i = 0; i < 4; ++i) {
            int f4 = tid + i * 256;      // 0..1023
            int r  = f4 >> 3;            // 0..127
            int kc = (f4 & 7) << 2;      // 0,4,...,28
            int gr = rowBase + r;
            float4 v = {0.f, 0.f, 0.f, 0.f};
            if (gr < N) v = *(const float4*)(Ap + (size_t)gr * HID + kb + kc);
            As[kc + 0][r] = v.x; As[kc + 1][r] = v.y;
            As[kc + 2][r] = v.z; As[kc + 3][r] = v.w;
        }
#pragma unroll
        for (int i = 0; i < 4; ++i) {
            int f4 = tid + i * 256;
            int k  = f4 >> 5;            // 0..31
            int c4 = (f4 & 31) << 2;     // 0..124
            *(float4*)&Ws[k][c4] = *(const float4*)(Wb + (size_t)(kb + k) * HID + c4);
        }
        __syncthreads();
#pragma unroll
        for (int k = 0; k < 32; ++k) {
            float a[8], w[8];
            *(float4*)&a[0] = *(const float4*)&As[k][tr * 8];
            *(float4*)&a[4] = *(const float4*)&As[k][tr * 8 + 4];
            *(float4*)&w[0] = *(const float4*)&Ws[k][tc * 4];
            *(float4*)&w[4] = *(const float4*)&Ws[k][64 + tc * 4];
#pragma unroll
            for (int i = 0; i < 8; ++i)
#pragma unroll
                for (int j = 0; j < 8; ++j)
                    acc[i][j] = fmaf(a[i], w[j], acc[i][j]);
        }
        __syncthreads();
    }
#pragma unroll
    for (int i = 0; i < 8; ++i) {
        int gr = rowBase + tr * 8 + i;
        if (gr < N) {
            ushort4 o0, o1;
            o0.x = f2bf(acc[i][0]); o0.y = f2bf(acc[i][1]);
            o0.z = f2bf(acc[i][2]); o0.w = f2bf(acc[i][3]);
            o1.x = f2bf(acc[i][4]); o1.y = f2bf(acc[i][5]);
            o1.z = f2bf(acc[i][6]); o1.w = f2bf(acc[i][7]);
            *(ushort4*)(C + (size_t)gr * HID + tc * 4) = o0;
            *(ushort4*)(C + (size_t)gr * HID + 64 + tc * 4) = o1;
        }
    }
}

// ---------------- CSR gather-aggregate + bias + ReLU ----------------
// one wave per destination node; t is bf16 (one dword/lane = 2 feats);
// 8 edges in flight, 4 interleaved accumulator pairs.
__global__ __launch_bounds__(256) void k_aggregate(const unsigned short* __restrict__ t,
                                                   const int* __restrict__ indptr,
                                                   const int* __restrict__ srcs,
                                                   const float* __restrict__ enorm,
                                                   const float* __restrict__ bias,
                                                   float* __restrict__ h, int N) {
    int node = blockIdx.x * 4 + (threadIdx.x >> 6);
    if (node >= N) return;
    int lane = threadIdx.x & 63;
    int s = indptr[node], e = indptr[node + 1];
    float ax[4] = {0.f, 0.f, 0.f, 0.f};
    float ay[4] = {0.f, 0.f, 0.f, 0.f};
    int p = s;
    for (; p + 7 < e; p += 8) {
        unsigned int v[8];
        float w[8];
#pragma unroll
        for (int u = 0; u < 8; ++u) {
            int ss = srcs[p + u];
            w[u] = enorm[p + u];
            v[u] = ((const unsigned int*)(t + (size_t)ss * HID))[lane];
        }
#pragma unroll
        for (int u = 0; u < 8; ++u) {
            float lo = bf2f((unsigned short)(v[u] & 0xffffu));
            float hi = bf2f((unsigned short)(v[u] >> 16));
            ax[u & 3] = fmaf(w[u], lo, ax[u & 3]);
            ay[u & 3] = fmaf(w[u], hi, ay[u & 3]);
        }
    }
    for (; p < e; ++p) {
        int ss = srcs[p];
        float ww = enorm[p];
        unsigned int v = ((const unsigned int*)(t + (size_t)ss * HID))[lane];
        ax[0] = fmaf(ww, bf2f((unsigned short)(v & 0xffffu)), ax[0]);
        ay[0] = fmaf(ww, bf2f((unsigned short)(v >> 16)), ay[0]);
    }
    float2 o;
    o.x = fmaxf((ax[0] + ax[1]) + (ax[2] + ax[3]) + bias[lane * 2], 0.f);
    o.y = fmaxf((ay[0] + ay[1]) + (ay[2] + ay[3]) + bias[lane * 2 + 1], 0.f);
    ((float2*)(h + (size_t)node * HID))[lane] = o;
}

// ---------------- segment mean-pool (batch is sorted) ----------------
__global__ void k_pool(const float* __restrict__ h, const int* __restrict__ gstart,
                       const int* __restrict__ cntG, float* __restrict__ pbuf, int layer) {
    int g = blockIdx.x;
    int c = threadIdx.x;  // 128 threads
    int s = gstart[g], e = gstart[g + 1];
    float sum = 0.f;
    for (int v = s; v < e; ++v) sum += h[(size_t)v * HID + c];
    float cnt = (float)cntG[g];
    pbuf[(size_t)g * 640 + layer * HID + c] = sum / fmaxf(cnt, 1.0f);
}

// ---------------- MLP head: Z[G,640] = relu(P[G,640] @ Wl1 + bl1) ------------
__global__ __launch_bounds__(256) void k_head1(const float* __restrict__ P,
                                               const float* __restrict__ Wl1,
                                               const float* __restrict__ bl1,
                                               float* __restrict__ Z, int G) {
    __shared__ float As[64][68];   // k-major: As[k][g], pad to 68
    __shared__ float Ws[64][64];   // Ws[k][c]
    const int tid = threadIdx.x;
    const int tr = tid >> 4;       // 0..15 -> local rows tr*4..+3
    const int tc = tid & 15;       // 0..15 -> local cols tc*4..+3
    const int gBase = blockIdx.x * 64;
    const int cBase = blockIdx.y * 64;

    float acc[4][4];
#pragma unroll
    for (int i = 0; i < 4; ++i)
#pragma unroll
        for (int j = 0; j < 4; ++j) acc[i][j] = 0.f;

    for (int kb = 0; kb < 640; kb += 64) {
#pragma unroll
        for (int i = 0; i < 4; ++i) {
            int f4 = tid + i * 256;        // 0..1023
            int r  = f4 >> 4;              // 0..63
            int kc = (f4 & 15) << 2;       // 0..60
            int gg = gBase + r;
            float4 v = {0.f, 0.f, 0.f, 0.f};
            if (gg < G) v = *(const float4*)(P + (size_t)gg * 640 + kb + kc);
            As[kc + 0][r] = v.x; As[kc + 1][r] = v.y;
            As[kc + 2][r] = v.z; As[kc + 3][r] = v.w;
        }
#pragma unroll
        for (int i = 0; i < 4; ++i) {
            int f4 = tid + i * 256;
            int k  = f4 >> 4;              // 0..63
            int c4 = (f4 & 15) << 2;       // 0..60
            *(float4*)&Ws[k][c4] =
                *(const float4*)(Wl1 + (size_t)(kb + k) * 640 + cBase + c4);
        }
        __syncthreads();
#pragma unroll
        for (int k = 0; k < 64; ++k) {
            float a[4], w[4];
            *(float4*)&a[0] = *(const float4*)&As[k][tr * 4];
            *(float4*)&w[0] = *(const float4*)&Ws[k][tc * 4];
#pragma unroll
            for (int i = 0; i < 4; ++i)
#pragma unroll
                for (int j = 0; j < 4; ++j)
                    acc[i][j] = fmaf(a[i], w[j], acc[i][j]);
        }
        __syncthreads();
    }
#pragma unroll
    for (int i = 0; i < 4; ++i) {
        int gg = gBase + tr * 4 + i;
        if (gg < G) {
            float4 o;
            o.x = fmaxf(acc[i][0] + bl1[cBase + tc * 4 + 0], 0.f);
            o.y = fmaxf(acc[i][1] + bl1[cBase + tc * 4 + 1], 0.f);
            o.z = fmaxf(acc[i][2] + bl1[cBase + tc * 4 + 2], 0.f);
            o.w = fmaxf(acc[i][3] + bl1[cBase + tc * 4 + 3], 0.f);
            *(float4*)(Z + (size_t)gg * 640 + cBase + tc * 4) = o;
        }
    }
}

__global__ void k_fc2(const float* __restrict__ zbuf, const float* __restrict__ Wl2,
                      const float* __restrict__ bl2, float* __restrict__ out) {
    int g = blockIdx.x;
    int t = threadIdx.x;  // 128 threads = 2 waves
    float s = 0.f;
    for (int k = t; k < 640; k += 128) s = fmaf(zbuf[(size_t)g * 640 + k], Wl2[k], s);
#pragma unroll
    for (int off = 32; off > 0; off >>= 1) s += __shfl_down(s, off);
    __shared__ float ws[2];
    if ((t & 63) == 0) ws[t >> 6] = s;
    __syncthreads();
    if (t == 0) out[g] = ws[0] + ws[1] + bl2[0];
}

// ---------------- driver ----------------
extern "C" void kernel_launch(void* const* d_in, const int* in_sizes, int n_in,
                              void* d_out, int out_size, void* d_ws, size_t ws_size,
                              hipStream_t stream) {
    const float* x    = (const float*)d_in[0];
    const int*   edge = (const int*)d_in[1];
    const int*   bat  = (const int*)d_in[2];
    const float* W1   = (const float*)d_in[3];
    const float* b1   = (const float*)d_in[4];
    const float* W2   = (const float*)d_in[5];
    const float* b2   = (const float*)d_in[6];
    const float* W3   = (const float*)d_in[7];
    const float* b3   = (const float*)d_in[8];
    const float* W4   = (const float*)d_in[9];
    const float* b4   = (const float*)d_in[10];
    const float* Wl1  = (const float*)d_in[11];
    const float* bl1  = (const float*)d_in[12];
    const float* Wl2  = (const float*)d_in[13];
    const float* bl2  = (const float*)d_in[14];
    float*       out  = (float*)d_out;

    const int N = in_sizes[2];       // 100000
    const int E = in_sizes[1] / 2;   // 1600000
    const int G = out_size;          // 512
    (void)n_in; (void)ws_size;

    (void)hipGetLastError();  // clear any stale error

    // ---- workspace carve ----
    size_t off = 0;
    auto alloc = [&](size_t bytes) -> void* {
        void* p = (void*)((char*)d_ws + off);
        off += (bytes + 255) & ~(size_t)255;
        return p;
    };
    unsigned short* buf0 = (unsigned short*)alloc((size_t)N * HID * 2);  // t, bf16
    float* buf1   = (float*)alloc((size_t)N * HID * 4);                  // h, f32
    float* dinv   = (float*)alloc((size_t)N * 4);
    int*   degI   = (int*)alloc((size_t)N * 4);
    int*   cursor = (int*)alloc((size_t)N * 4);
    int*   indptr = (int*)alloc((size_t)(N + 1) * 4);
    int*   partial= (int*)alloc((size_t)N * 4);
    int*   bsums  = (int*)alloc((size_t)1024 * 4);
    int*   srcs   = (int*)alloc((size_t)(E + N) * 4);
    float* enorm  = (float*)alloc((size_t)(E + N) * 4);
    int*   cntG   = (int*)alloc((size_t)G * 4);
    int*   gstart = (int*)alloc((size_t)(G + 1) * 4);
    float* pbuf   = (float*)alloc((size_t)G * 640 * 4);
    float* zbuf   = (float*)alloc((size_t)G * 640 * 4);

    const int* rowv = edge;      // sources
    const int* colv = edge + E;  // destinations

    // ---- preprocessing (once, reused by all 5 convs) ----
    hipMemsetAsync(degI, 0, (size_t)N * 4, stream);
    hipMemsetAsync(cntG, 0, (size_t)G * 4, stream);
    k_deg<<<(E + 255) / 256, 256, 0, stream>>>(colv, degI, E);
    k_dinv<<<(N + 255) / 256, 256, 0, stream>>>(degI, dinv, N);
    const int scanBlocks = (N + 1023) / 1024;
    k_scan_part<<<scanBlocks, 1024, 0, stream>>>(degI, partial, bsums, N);
    k_scan_tops<<<1, 1024, 0, stream>>>(bsums, indptr, scanBlocks, N);
    k_scan_fix<<<(N + 255) / 256, 256, 0, stream>>>(partial, bsums, indptr, cursor, N);
    k_scatter<<<(E + N + 255) / 256, 256, 0, stream>>>(rowv, colv, dinv, cursor,
                                                       srcs, enorm, E, N);
    k_ghist<<<(N + 255) / 256, 256, 0, stream>>>(bat, cntG, N);
    k_gscan<<<1, 512, 0, stream>>>(cntG, gstart, G);

    // ---- 5 GCN layers (layer 5 reuses W4/b4, matching the reference) ----
    const float* Ws_[5] = {W1, W2, W3, W4, W4};
    const float* bs_[5] = {b1, b2, b3, b4, b4};
    const int gemmGrid = (N + 127) / 128;
    const int aggGrid  = (N + 3) / 4;
    for (int L = 0; L < 5; ++L) {
        const float* src = (L == 0) ? x : buf1;
        k_gemm128<<<gemmGrid, 256, 0, stream>>>(src, Ws_[L], buf0, N);
        k_aggregate<<<aggGrid, 256, 0, stream>>>(buf0, indptr, srcs, enorm, bs_[L], buf1, N);
        k_pool<<<G, 128, 0, stream>>>(buf1, gstart, cntG, pbuf, L);
    }

    // ---- MLP head ----
    dim3 hgrid((G + 63) / 64, 10);   // 640 output cols / 64
    k_head1<<<hgrid, 256, 0, stream>>>(pbuf, Wl1, bl1, zbuf, G);
    k_fc2<<<G, 128, 0, stream>>>(zbuf, Wl2, bl2, out);

    // sentinel: some launch failed synchronously (absmax ~= 48)
    if (hipGetLastError() != hipSuccess)
        hipMemsetAsync(d_out, 0x42, (size_t)out_size * 4, stream);
}

// Round 7
// 1232.642 us; speedup vs baseline: 1.7293x; 1.1285x over previous
//
#include <hip/hip_runtime.h>

#define HID 128   // feature width (D == H == 128)

// ---------------- bf16 helpers ----------------
__device__ __forceinline__ float bf2f(unsigned short u) {
    union { unsigned int i; float f; } v;
    v.i = ((unsigned int)u) << 16;
    return v.f;
}
__device__ __forceinline__ unsigned short f2bf(float f) {
    union { float f; unsigned int i; } v;
    v.f = f;
    unsigned int lsb = (v.i >> 16) & 1u;
    v.i += 0x7fffu + lsb;   // round-to-nearest-even
    return (unsigned short)(v.i >> 16);
}

typedef __attribute__((ext_vector_type(8))) short bf16x8;   // 8 bf16 (4 VGPRs)
typedef __attribute__((ext_vector_type(4))) float f32x4;    // MFMA acc

// ---------------- preprocessing ----------------
__global__ void k_deg(const int* __restrict__ col, int* __restrict__ degI, int E) {
    int i = blockIdx.x * blockDim.x + threadIdx.x;
    if (i < E) atomicAdd(&degI[col[i]], 1);
}

__global__ void k_dinv(const int* __restrict__ degI, float* __restrict__ dinv, int N) {
    int i = blockIdx.x * blockDim.x + threadIdx.x;
    if (i < N) dinv[i] = 1.0f / sqrtf((float)(degI[i] + 1));  // +1 self loop
}

// ---- 3-phase device-wide exclusive scan of (degI[i]+1) -> indptr, cursor ----
__global__ void k_scan_part(const int* __restrict__ degI, int* __restrict__ partial,
                            int* __restrict__ sums, int N) {
    __shared__ int sh[1024];
    int tid = threadIdx.x;
    int i = blockIdx.x * 1024 + tid;
    int v = (i < N) ? (degI[i] + 1) : 0;
    sh[tid] = v;
    __syncthreads();
    for (int off = 1; off < 1024; off <<= 1) {
        int t = (tid >= off) ? sh[tid - off] : 0;
        __syncthreads();
        sh[tid] += t;
        __syncthreads();
    }
    if (i < N) partial[i] = sh[tid] - v;
    if (tid == 1023) sums[blockIdx.x] = sh[1023];
}
__global__ void k_scan_tops(int* __restrict__ sums, int* __restrict__ indptr,
                            int nblocks, int N) {
    __shared__ int sh[1024];
    int tid = threadIdx.x;
    int v = (tid < nblocks) ? sums[tid] : 0;
    sh[tid] = v;
    __syncthreads();
    for (int off = 1; off < 1024; off <<= 1) {
        int t = (tid >= off) ? sh[tid - off] : 0;
        __syncthreads();
        sh[tid] += t;
        __syncthreads();
    }
    if (tid < nblocks) sums[tid] = sh[tid] - v;   // exclusive
    if (tid == 1023) indptr[N] = sh[1023];        // grand total = E + N
}
__global__ void k_scan_fix(const int* __restrict__ partial, const int* __restrict__ sums,
                           int* __restrict__ indptr, int* __restrict__ cursor, int N) {
    int i = blockIdx.x * blockDim.x + threadIdx.x;
    if (i < N) {
        int ex = partial[i] + sums[i >> 10];
        indptr[i] = ex;
        cursor[i] = ex;
    }
}

// scatter edges (and self loops) into CSR-by-destination.
// (src, norm) packed as one int2 -> single 8B random store per edge
// (halves write-allocate line traffic vs two 4B stores).
__global__ void k_scatter(const int* __restrict__ row, const int* __restrict__ col,
                          const float* __restrict__ dinv, int* __restrict__ cursor,
                          int2* __restrict__ adj, int E, int N) {
    int e = blockIdx.x * blockDim.x + threadIdx.x;
    if (e >= E + N) return;
    int s, d;
    if (e < E) { s = row[e]; d = col[e]; }
    else       { s = d = e - E; }          // self loop
    int p = atomicAdd(&cursor[d], 1);
    float nrm = dinv[s] * dinv[d];
    adj[p] = make_int2(s, __float_as_int(nrm));
}

__global__ void k_ghist(const int* __restrict__ batch, int* __restrict__ cntG, int N) {
    int i = blockIdx.x * blockDim.x + threadIdx.x;
    if (i < N) atomicAdd(&cntG[batch[i]], 1);
}

__global__ void k_gscan(const int* __restrict__ cntG, int* __restrict__ gstart, int G) {
    __shared__ int sh[512];
    int tid = threadIdx.x;
    int v = (tid < G) ? cntG[tid] : 0;
    sh[tid] = v;
    __syncthreads();
    for (int off = 1; off < 512; off <<= 1) {
        int t = (tid >= off) ? sh[tid - off] : 0;
        __syncthreads();
        sh[tid] += t;
        __syncthreads();
    }
    if (tid < G) gstart[tid] = sh[tid] - v;
    if (tid == 511) gstart[G] = sh[511];
}

// ---------------- MFMA GEMM: T[N,128](bf16) = A[N,128] @ W[128,128](f32) -----
// 128 rows/block, 4 waves; wave w -> rows w*32..+31 as 2x8 grid of 16x16 MFMA
// tiles, K=128 in 4 steps of 32. W converted f32->bf16 and swizzled into LDS
// in exact B-fragment order: one ds_read_b128 per fragment.
// Fragment layouts (m89/m91/m120 verified):
//   A: lane(q=lane>>4, c=lane&15) holds A[m=c][k=q*8+j], j=0..7 (16B contig)
//   B: lane holds B[k=q*8+j][n=c]
//   C/D: col=c, row=q*4+reg
__device__ __forceinline__ bf16x8 a_frag_load(const unsigned short* p) {
    return *(const bf16x8*)p;
}
__device__ __forceinline__ bf16x8 a_frag_load(const float* p) {
    bf16x8 r;
#pragma unroll
    for (int i = 0; i < 8; ++i) r[i] = (short)f2bf(p[i]);
    return r;
}

template <typename TA>
__global__ __launch_bounds__(256) void k_gemm_mfma(const TA* __restrict__ A,
                                                   const float* __restrict__ W,
                                                   unsigned short* __restrict__ C,
                                                   int N) {
    __shared__ unsigned short Wsw[16384];   // 32 KB swizzled bf16 W
    const int tid = threadIdx.x;
    // stage W: linear (coalesced) read, swizzled LDS write
    for (int i = tid; i < 16384; i += 256) {
        int k = i >> 7;          // 0..127
        int n = i & 127;         // 0..127
        int ks = k >> 5, q = (k >> 3) & 3, j = k & 7;
        int ct = n >> 4, c = n & 15;
        int dst = ((((ks * 8 + ct) * 4 + q) * 16 + c) << 3) + j;
        Wsw[dst] = f2bf(W[i]);
    }
    __syncthreads();

    const int lane = tid & 63, wave = tid >> 6;
    const int q = lane >> 4, c = lane & 15;
    const int rowBase = blockIdx.x * 128 + wave * 32;

    f32x4 acc[2][8];
#pragma unroll
    for (int rt = 0; rt < 2; ++rt)
#pragma unroll
        for (int ct = 0; ct < 8; ++ct)
            acc[rt][ct] = (f32x4){0.f, 0.f, 0.f, 0.f};

    const bf16x8 zfrag = {};
#pragma unroll
    for (int ks = 0; ks < 4; ++ks) {
        bf16x8 a[2];
#pragma unroll
        for (int rt = 0; rt < 2; ++rt) {
            int r = rowBase + rt * 16 + c;
            a[rt] = (r < N) ? a_frag_load(A + (size_t)r * HID + ks * 32 + q * 8)
                            : zfrag;
        }
#pragma unroll
        for (int ct = 0; ct < 8; ++ct) {
            bf16x8 b = *(const bf16x8*)&Wsw[((((ks * 8 + ct) * 4 + q) * 16 + c) << 3)];
            acc[0][ct] = __builtin_amdgcn_mfma_f32_16x16x32_bf16(a[0], b, acc[0][ct], 0, 0, 0);
            acc[1][ct] = __builtin_amdgcn_mfma_f32_16x16x32_bf16(a[1], b, acc[1][ct], 0, 0, 0);
        }
    }
    // epilogue: C/D row = q*4+reg, col = c
#pragma unroll
    for (int rt = 0; rt < 2; ++rt)
#pragma unroll
        for (int reg = 0; reg < 4; ++reg) {
            int r = rowBase + rt * 16 + q * 4 + reg;
            if (r < N) {
#pragma unroll
                for (int ct = 0; ct < 8; ++ct)
                    C[(size_t)r * HID + ct * 16 + c] = f2bf(acc[rt][ct][reg]);
            }
        }
}

// ---------------- CSR gather-aggregate + bias + ReLU ----------------
// one wave per destination node; t bf16 (one dword/lane = 2 feats);
// 8 edges in flight; h output bf16 (feeds next MFMA GEMM + pool).
__global__ __launch_bounds__(256) void k_aggregate(const unsigned short* __restrict__ t,
                                                   const int* __restrict__ indptr,
                                                   const int2* __restrict__ adj,
                                                   const float* __restrict__ bias,
                                                   unsigned short* __restrict__ h, int N) {
    int node = blockIdx.x * 4 + (threadIdx.x >> 6);
    if (node >= N) return;
    int lane = threadIdx.x & 63;
    int s = indptr[node], e = indptr[node + 1];
    float ax[4] = {0.f, 0.f, 0.f, 0.f};
    float ay[4] = {0.f, 0.f, 0.f, 0.f};
    int p = s;
    for (; p + 7 < e; p += 8) {
        unsigned int v[8];
        float w[8];
#pragma unroll
        for (int u = 0; u < 8; ++u) {
            int2 ae = adj[p + u];
            w[u] = __int_as_float(ae.y);
            v[u] = ((const unsigned int*)(t + (size_t)ae.x * HID))[lane];
        }
#pragma unroll
        for (int u = 0; u < 8; ++u) {
            float lo = bf2f((unsigned short)(v[u] & 0xffffu));
            float hi = bf2f((unsigned short)(v[u] >> 16));
            ax[u & 3] = fmaf(w[u], lo, ax[u & 3]);
            ay[u & 3] = fmaf(w[u], hi, ay[u & 3]);
        }
    }
    for (; p < e; ++p) {
        int2 ae = adj[p];
        float ww = __int_as_float(ae.y);
        unsigned int v = ((const unsigned int*)(t + (size_t)ae.x * HID))[lane];
        ax[0] = fmaf(ww, bf2f((unsigned short)(v & 0xffffu)), ax[0]);
        ay[0] = fmaf(ww, bf2f((unsigned short)(v >> 16)), ay[0]);
    }
    float ox = fmaxf((ax[0] + ax[1]) + (ax[2] + ax[3]) + bias[lane * 2], 0.f);
    float oy = fmaxf((ay[0] + ay[1]) + (ay[2] + ay[3]) + bias[lane * 2 + 1], 0.f);
    unsigned int pk = (unsigned int)f2bf(ox) | ((unsigned int)f2bf(oy) << 16);
    ((unsigned int*)(h + (size_t)node * HID))[lane] = pk;
}

// ---------------- segment mean-pool (batch is sorted; h bf16) ----------------
__global__ void k_pool(const unsigned short* __restrict__ h, const int* __restrict__ gstart,
                       const int* __restrict__ cntG, float* __restrict__ pbuf, int layer) {
    int g = blockIdx.x;
    int c = threadIdx.x;  // 128 threads
    int s = gstart[g], e = gstart[g + 1];
    float sum = 0.f;
    for (int v = s; v < e; ++v) sum += bf2f(h[(size_t)v * HID + c]);
    float cnt = (float)cntG[g];
    pbuf[(size_t)g * 640 + layer * HID + c] = sum / fmaxf(cnt, 1.0f);
}

// ---------------- MLP head: Z[G,640] = relu(P[G,640] @ Wl1 + bl1) ------------
__global__ __launch_bounds__(256) void k_head1(const float* __restrict__ P,
                                               const float* __restrict__ Wl1,
                                               const float* __restrict__ bl1,
                                               float* __restrict__ Z, int G) {
    __shared__ float As[64][68];   // k-major: As[k][g], pad to 68
    __shared__ float Ws[64][64];   // Ws[k][c]
    const int tid = threadIdx.x;
    const int tr = tid >> 4;
    const int tc = tid & 15;
    const int gBase = blockIdx.x * 64;
    const int cBase = blockIdx.y * 64;

    float acc[4][4];
#pragma unroll
    for (int i = 0; i < 4; ++i)
#pragma unroll
        for (int j = 0; j < 4; ++j) acc[i][j] = 0.f;

    for (int kb = 0; kb < 640; kb += 64) {
#pragma unroll
        for (int i = 0; i < 4; ++i) {
            int f4 = tid + i * 256;
            int r  = f4 >> 4;
            int kc = (f4 & 15) << 2;
            int gg = gBase + r;
            float4 v = {0.f, 0.f, 0.f, 0.f};
            if (gg < G) v = *(const float4*)(P + (size_t)gg * 640 + kb + kc);
            As[kc + 0][r] = v.x; As[kc + 1][r] = v.y;
            As[kc + 2][r] = v.z; As[kc + 3][r] = v.w;
        }
#pragma unroll
        for (int i = 0; i < 4; ++i) {
            int f4 = tid + i * 256;
            int k  = f4 >> 4;
            int c4 = (f4 & 15) << 2;
            *(float4*)&Ws[k][c4] =
                *(const float4*)(Wl1 + (size_t)(kb + k) * 640 + cBase + c4);
        }
        __syncthreads();
#pragma unroll
        for (int k = 0; k < 64; ++k) {
            float a[4], w[4];
            *(float4*)&a[0] = *(const float4*)&As[k][tr * 4];
            *(float4*)&w[0] = *(const float4*)&Ws[k][tc * 4];
#pragma unroll
            for (int i = 0; i < 4; ++i)
#pragma unroll
                for (int j = 0; j < 4; ++j)
                    acc[i][j] = fmaf(a[i], w[j], acc[i][j]);
        }
        __syncthreads();
    }
#pragma unroll
    for (int i = 0; i < 4; ++i) {
        int gg = gBase + tr * 4 + i;
        if (gg < G) {
            float4 o;
            o.x = fmaxf(acc[i][0] + bl1[cBase + tc * 4 + 0], 0.f);
            o.y = fmaxf(acc[i][1] + bl1[cBase + tc * 4 + 1], 0.f);
            o.z = fmaxf(acc[i][2] + bl1[cBase + tc * 4 + 2], 0.f);
            o.w = fmaxf(acc[i][3] + bl1[cBase + tc * 4 + 3], 0.f);
            *(float4*)(Z + (size_t)gg * 640 + cBase + tc * 4) = o;
        }
    }
}

__global__ void k_fc2(const float* __restrict__ zbuf, const float* __restrict__ Wl2,
                      const float* __restrict__ bl2, float* __restrict__ out) {
    int g = blockIdx.x;
    int t = threadIdx.x;  // 128 threads = 2 waves
    float s = 0.f;
    for (int k = t; k < 640; k += 128) s = fmaf(zbuf[(size_t)g * 640 + k], Wl2[k], s);
#pragma unroll
    for (int off = 32; off > 0; off >>= 1) s += __shfl_down(s, off);
    __shared__ float ws[2];
    if ((t & 63) == 0) ws[t >> 6] = s;
    __syncthreads();
    if (t == 0) out[g] = ws[0] + ws[1] + bl2[0];
}

// ---------------- driver ----------------
extern "C" void kernel_launch(void* const* d_in, const int* in_sizes, int n_in,
                              void* d_out, int out_size, void* d_ws, size_t ws_size,
                              hipStream_t stream) {
    const float* x    = (const float*)d_in[0];
    const int*   edge = (const int*)d_in[1];
    const int*   bat  = (const int*)d_in[2];
    const float* W1   = (const float*)d_in[3];
    const float* b1   = (const float*)d_in[4];
    const float* W2   = (const float*)d_in[5];
    const float* b2   = (const float*)d_in[6];
    const float* W3   = (const float*)d_in[7];
    const float* b3   = (const float*)d_in[8];
    const float* W4   = (const float*)d_in[9];
    const float* b4   = (const float*)d_in[10];
    const float* Wl1  = (const float*)d_in[11];
    const float* bl1  = (const float*)d_in[12];
    const float* Wl2  = (const float*)d_in[13];
    const float* bl2  = (const float*)d_in[14];
    float*       out  = (float*)d_out;

    const int N = in_sizes[2];       // 100000
    const int E = in_sizes[1] / 2;   // 1600000
    const int G = out_size;          // 512
    (void)n_in; (void)ws_size;

    (void)hipGetLastError();  // clear any stale error

    // ---- workspace carve ----
    size_t off = 0;
    auto alloc = [&](size_t bytes) -> void* {
        void* p = (void*)((char*)d_ws + off);
        off += (bytes + 255) & ~(size_t)255;
        return p;
    };
    unsigned short* buf0 = (unsigned short*)alloc((size_t)N * HID * 2);  // t, bf16
    unsigned short* buf1 = (unsigned short*)alloc((size_t)N * HID * 2);  // h, bf16
    float* dinv   = (float*)alloc((size_t)N * 4);
    int*   degI   = (int*)alloc((size_t)N * 4);
    int*   cursor = (int*)alloc((size_t)N * 4);
    int*   indptr = (int*)alloc((size_t)(N + 1) * 4);
    int*   partial= (int*)alloc((size_t)N * 4);
    int*   bsums  = (int*)alloc((size_t)1024 * 4);
    int2*  adj    = (int2*)alloc((size_t)(E + N) * 8);
    int*   cntG   = (int*)alloc((size_t)G * 4);
    int*   gstart = (int*)alloc((size_t)(G + 1) * 4);
    float* pbuf   = (float*)alloc((size_t)G * 640 * 4);
    float* zbuf   = (float*)alloc((size_t)G * 640 * 4);

    const int* rowv = edge;      // sources
    const int* colv = edge + E;  // destinations

    // ---- preprocessing (once, reused by all 5 convs) ----
    hipMemsetAsync(degI, 0, (size_t)N * 4, stream);
    hipMemsetAsync(cntG, 0, (size_t)G * 4, stream);
    k_deg<<<(E + 255) / 256, 256, 0, stream>>>(colv, degI, E);
    k_dinv<<<(N + 255) / 256, 256, 0, stream>>>(degI, dinv, N);
    const int scanBlocks = (N + 1023) / 1024;
    k_scan_part<<<scanBlocks, 1024, 0, stream>>>(degI, partial, bsums, N);
    k_scan_tops<<<1, 1024, 0, stream>>>(bsums, indptr, scanBlocks, N);
    k_scan_fix<<<(N + 255) / 256, 256, 0, stream>>>(partial, bsums, indptr, cursor, N);
    k_scatter<<<(E + N + 255) / 256, 256, 0, stream>>>(rowv, colv, dinv, cursor,
                                                       adj, E, N);
    k_ghist<<<(N + 255) / 256, 256, 0, stream>>>(bat, cntG, N);
    k_gscan<<<1, 512, 0, stream>>>(cntG, gstart, G);

    // ---- 5 GCN layers (layer 5 reuses W4/b4, matching the reference) ----
    const float* Ws_[5] = {W1, W2, W3, W4, W4};
    const float* bs_[5] = {b1, b2, b3, b4, b4};
    const int gemmGrid = (N + 127) / 128;
    const int aggGrid  = (N + 3) / 4;
    for (int L = 0; L < 5; ++L) {
        if (L == 0)
            k_gemm_mfma<float><<<gemmGrid, 256, 0, stream>>>(x, Ws_[0], buf0, N);
        else
            k_gemm_mfma<unsigned short><<<gemmGrid, 256, 0, stream>>>(buf1, Ws_[L], buf0, N);
        k_aggregate<<<aggGrid, 256, 0, stream>>>(buf0, indptr, adj, bs_[L], buf1, N);
        k_pool<<<G, 128, 0, stream>>>(buf1, gstart, cntG, pbuf, L);
    }

    // ---- MLP head ----
    dim3 hgrid((G + 63) / 64, 10);   // 640 output cols / 64
    k_head1<<<hgrid, 256, 0, stream>>>(pbuf, Wl1, bl1, zbuf, G);
    k_fc2<<<G, 128, 0, stream>>>(zbuf, Wl2, bl2, out);

    // sentinel: some launch failed synchronously (absmax ~= 48)
    if (hipGetLastError() != hipSuccess)
        hipMemsetAsync(d_out, 0x42, (size_t)out_size * 4, stream);
}

// Round 8
// 976.410 us; speedup vs baseline: 2.1831x; 1.2624x over previous
//
#include <hip/hip_runtime.h>

#define HID 128   // feature width (D == H == 128)

// ---------------- bf16 helpers ----------------
__device__ __forceinline__ float bf2f(unsigned short u) {
    union { unsigned int i; float f; } v;
    v.i = ((unsigned int)u) << 16;
    return v.f;
}
__device__ __forceinline__ unsigned short f2bf(float f) {
    union { float f; unsigned int i; } v;
    v.f = f;
    unsigned int lsb = (v.i >> 16) & 1u;
    v.i += 0x7fffu + lsb;   // round-to-nearest-even
    return (unsigned short)(v.i >> 16);
}

typedef __attribute__((ext_vector_type(8))) short bf16x8;   // 8 bf16 (4 VGPRs)
typedef __attribute__((ext_vector_type(4))) float f32x4;    // MFMA acc

// ---------------- preprocessing ----------------
__global__ void k_deg(const int* __restrict__ col, int* __restrict__ degI, int E) {
    int i = blockIdx.x * blockDim.x + threadIdx.x;
    if (i < E) atomicAdd(&degI[col[i]], 1);
}

__global__ void k_dinv(const int* __restrict__ degI, float* __restrict__ dinv, int N) {
    int i = blockIdx.x * blockDim.x + threadIdx.x;
    if (i < N) dinv[i] = 1.0f / sqrtf((float)(degI[i] + 1));  // +1 self loop
}

// ---- 3-phase device-wide exclusive scan of (degI[i]+1) -> indptr, cursor ----
__global__ void k_scan_part(const int* __restrict__ degI, int* __restrict__ partial,
                            int* __restrict__ sums, int N) {
    __shared__ int sh[1024];
    int tid = threadIdx.x;
    int i = blockIdx.x * 1024 + tid;
    int v = (i < N) ? (degI[i] + 1) : 0;
    sh[tid] = v;
    __syncthreads();
    for (int off = 1; off < 1024; off <<= 1) {
        int t = (tid >= off) ? sh[tid - off] : 0;
        __syncthreads();
        sh[tid] += t;
        __syncthreads();
    }
    if (i < N) partial[i] = sh[tid] - v;
    if (tid == 1023) sums[blockIdx.x] = sh[1023];
}
__global__ void k_scan_tops(int* __restrict__ sums, int* __restrict__ indptr,
                            int nblocks, int N) {
    __shared__ int sh[1024];
    int tid = threadIdx.x;
    int v = (tid < nblocks) ? sums[tid] : 0;
    sh[tid] = v;
    __syncthreads();
    for (int off = 1; off < 1024; off <<= 1) {
        int t = (tid >= off) ? sh[tid - off] : 0;
        __syncthreads();
        sh[tid] += t;
        __syncthreads();
    }
    if (tid < nblocks) sums[tid] = sh[tid] - v;   // exclusive
    if (tid == 1023) indptr[N] = sh[1023];        // grand total = E + N
}
__global__ void k_scan_fix(const int* __restrict__ partial, const int* __restrict__ sums,
                           int* __restrict__ indptr, int* __restrict__ cursor, int N) {
    int i = blockIdx.x * blockDim.x + threadIdx.x;
    if (i < N) {
        int ex = partial[i] + sums[i >> 10];
        indptr[i] = ex;
        cursor[i] = ex;
    }
}

// XCD-bucketed CSR scatter: blockIdx&7 selects a destination range (~N/8).
// With round-robin block->XCD dispatch, each range's 1.7MB output window stays
// resident in ONE XCD's L2 and every line receives all its 8B entries before
// eviction -> full-line writes (vs 104MB of partial-line evictions before).
// Correct regardless of actual XCD placement (pure filter partition).
__global__ void k_scatter(const int* __restrict__ row, const int* __restrict__ col,
                          const float* __restrict__ dinv, int* __restrict__ cursor,
                          int2* __restrict__ adj, int E, int N, int S) {
    const int g = blockIdx.x & 7;     // dest-range group (~XCD)
    const int s = blockIdx.x >> 3;    // edge-slice index, 0..S-1
    const int lo = (int)(((long long)g * N) >> 3);
    const int hi = (int)(((long long)(g + 1) * N) >> 3);
    const int total = E + N;
    const int per = (total + S - 1) / S;
    const int begin = s * per;
    const int end = (begin + per < total) ? begin + per : total;
    for (int e = begin + threadIdx.x; e < end; e += blockDim.x) {
        int sn, d;
        if (e < E) {
            d = col[e];
            if (d < lo || d >= hi) continue;
            sn = row[e];
        } else {
            d = e - E;                 // self loop
            if (d < lo || d >= hi) continue;
            sn = d;
        }
        int p = atomicAdd(&cursor[d], 1);
        adj[p] = make_int2(sn, __float_as_int(dinv[sn] * dinv[d]));
    }
}

__global__ void k_ghist(const int* __restrict__ batch, int* __restrict__ cntG, int N) {
    int i = blockIdx.x * blockDim.x + threadIdx.x;
    if (i < N) atomicAdd(&cntG[batch[i]], 1);
}

__global__ void k_gscan(const int* __restrict__ cntG, int* __restrict__ gstart, int G) {
    __shared__ int sh[512];
    int tid = threadIdx.x;
    int v = (tid < G) ? cntG[tid] : 0;
    sh[tid] = v;
    __syncthreads();
    for (int off = 1; off < 512; off <<= 1) {
        int t = (tid >= off) ? sh[tid - off] : 0;
        __syncthreads();
        sh[tid] += t;
        __syncthreads();
    }
    if (tid < G) gstart[tid] = sh[tid] - v;
    if (tid == 511) gstart[G] = sh[511];
}

// ---------------- MFMA GEMM: T[N,128](bf16) = A[N,128] @ W[128,128](f32) -----
__device__ __forceinline__ bf16x8 a_frag_load(const unsigned short* p) {
    return *(const bf16x8*)p;
}
__device__ __forceinline__ bf16x8 a_frag_load(const float* p) {
    bf16x8 r;
#pragma unroll
    for (int i = 0; i < 8; ++i) r[i] = (short)f2bf(p[i]);
    return r;
}

template <typename TA>
__global__ __launch_bounds__(256) void k_gemm_mfma(const TA* __restrict__ A,
                                                   const float* __restrict__ W,
                                                   unsigned short* __restrict__ C,
                                                   int N) {
    __shared__ unsigned short Wsw[16384];   // 32 KB swizzled bf16 W
    const int tid = threadIdx.x;
    for (int i = tid; i < 16384; i += 256) {
        int k = i >> 7;          // 0..127
        int n = i & 127;         // 0..127
        int ks = k >> 5, q = (k >> 3) & 3, j = k & 7;
        int ct = n >> 4, c = n & 15;
        int dst = ((((ks * 8 + ct) * 4 + q) * 16 + c) << 3) + j;
        Wsw[dst] = f2bf(W[i]);
    }
    __syncthreads();

    const int lane = tid & 63, wave = tid >> 6;
    const int q = lane >> 4, c = lane & 15;
    const int rowBase = blockIdx.x * 128 + wave * 32;

    f32x4 acc[2][8];
#pragma unroll
    for (int rt = 0; rt < 2; ++rt)
#pragma unroll
        for (int ct = 0; ct < 8; ++ct)
            acc[rt][ct] = (f32x4){0.f, 0.f, 0.f, 0.f};

    const bf16x8 zfrag = {};
#pragma unroll
    for (int ks = 0; ks < 4; ++ks) {
        bf16x8 a[2];
#pragma unroll
        for (int rt = 0; rt < 2; ++rt) {
            int r = rowBase + rt * 16 + c;
            a[rt] = (r < N) ? a_frag_load(A + (size_t)r * HID + ks * 32 + q * 8)
                            : zfrag;
        }
#pragma unroll
        for (int ct = 0; ct < 8; ++ct) {
            bf16x8 b = *(const bf16x8*)&Wsw[((((ks * 8 + ct) * 4 + q) * 16 + c) << 3)];
            acc[0][ct] = __builtin_amdgcn_mfma_f32_16x16x32_bf16(a[0], b, acc[0][ct], 0, 0, 0);
            acc[1][ct] = __builtin_amdgcn_mfma_f32_16x16x32_bf16(a[1], b, acc[1][ct], 0, 0, 0);
        }
    }
#pragma unroll
    for (int rt = 0; rt < 2; ++rt)
#pragma unroll
        for (int reg = 0; reg < 4; ++reg) {
            int r = rowBase + rt * 16 + q * 4 + reg;
            if (r < N) {
#pragma unroll
                for (int ct = 0; ct < 8; ++ct)
                    C[(size_t)r * HID + ct * 16 + c] = f2bf(acc[rt][ct][reg]);
            }
        }
}

// ---------------- CSR gather-aggregate + bias + ReLU ----------------
__global__ __launch_bounds__(256) void k_aggregate(const unsigned short* __restrict__ t,
                                                   const int* __restrict__ indptr,
                                                   const int2* __restrict__ adj,
                                                   const float* __restrict__ bias,
                                                   unsigned short* __restrict__ h, int N) {
    int node = blockIdx.x * 4 + (threadIdx.x >> 6);
    if (node >= N) return;
    int lane = threadIdx.x & 63;
    int s = indptr[node], e = indptr[node + 1];
    float ax[4] = {0.f, 0.f, 0.f, 0.f};
    float ay[4] = {0.f, 0.f, 0.f, 0.f};
    int p = s;
    for (; p + 7 < e; p += 8) {
        unsigned int v[8];
        float w[8];
#pragma unroll
        for (int u = 0; u < 8; ++u) {
            int2 ae = adj[p + u];
            w[u] = __int_as_float(ae.y);
            v[u] = ((const unsigned int*)(t + (size_t)ae.x * HID))[lane];
        }
#pragma unroll
        for (int u = 0; u < 8; ++u) {
            float lo = bf2f((unsigned short)(v[u] & 0xffffu));
            float hi = bf2f((unsigned short)(v[u] >> 16));
            ax[u & 3] = fmaf(w[u], lo, ax[u & 3]);
            ay[u & 3] = fmaf(w[u], hi, ay[u & 3]);
        }
    }
    for (; p < e; ++p) {
        int2 ae = adj[p];
        float ww = __int_as_float(ae.y);
        unsigned int v = ((const unsigned int*)(t + (size_t)ae.x * HID))[lane];
        ax[0] = fmaf(ww, bf2f((unsigned short)(v & 0xffffu)), ax[0]);
        ay[0] = fmaf(ww, bf2f((unsigned short)(v >> 16)), ay[0]);
    }
    float ox = fmaxf((ax[0] + ax[1]) + (ax[2] + ax[3]) + bias[lane * 2], 0.f);
    float oy = fmaxf((ay[0] + ay[1]) + (ay[2] + ay[3]) + bias[lane * 2 + 1], 0.f);
    unsigned int pk = (unsigned int)f2bf(ox) | ((unsigned int)f2bf(oy) << 16);
    ((unsigned int*)(h + (size_t)node * HID))[lane] = pk;
}

// ---------------- segment mean-pool: one wave per graph, 8-deep unroll -------
// lane reads one dword (2 cols) per node; 8 independent row-loads in flight
// (replaces the 2-byte-load serial-latency version).
__global__ __launch_bounds__(256) void k_pool(const unsigned short* __restrict__ h,
                                              const int* __restrict__ gstart,
                                              const int* __restrict__ cntG,
                                              float* __restrict__ pbuf,
                                              int layer, int G) {
    int g = blockIdx.x * 4 + (threadIdx.x >> 6);
    if (g >= G) return;
    int lane = threadIdx.x & 63;
    int s = gstart[g], e = gstart[g + 1];
    float sx[4] = {0.f, 0.f, 0.f, 0.f};
    float sy[4] = {0.f, 0.f, 0.f, 0.f};
    int v = s;
    for (; v + 7 < e; v += 8) {
        unsigned int pk[8];
#pragma unroll
        for (int u = 0; u < 8; ++u)
            pk[u] = ((const unsigned int*)(h + (size_t)(v + u) * HID))[lane];
#pragma unroll
        for (int u = 0; u < 8; ++u) {
            sx[u & 3] += bf2f((unsigned short)(pk[u] & 0xffffu));
            sy[u & 3] += bf2f((unsigned short)(pk[u] >> 16));
        }
    }
    for (; v < e; ++v) {
        unsigned int pk = ((const unsigned int*)(h + (size_t)v * HID))[lane];
        sx[0] += bf2f((unsigned short)(pk & 0xffffu));
        sy[0] += bf2f((unsigned short)(pk >> 16));
    }
    float inv = 1.0f / fmaxf((float)cntG[g], 1.0f);
    float ox = ((sx[0] + sx[1]) + (sx[2] + sx[3])) * inv;
    float oy = ((sy[0] + sy[1]) + (sy[2] + sy[3])) * inv;
    float* dst = pbuf + (size_t)g * 640 + layer * HID + lane * 2;
    dst[0] = ox;
    dst[1] = oy;
}

// ---------------- MLP head: Z[G,640] = relu(P[G,640] @ Wl1 + bl1) ------------
__global__ __launch_bounds__(256) void k_head1(const float* __restrict__ P,
                                               const float* __restrict__ Wl1,
                                               const float* __restrict__ bl1,
                                               float* __restrict__ Z, int G) {
    __shared__ float As[64][68];
    __shared__ float Ws[64][64];
    const int tid = threadIdx.x;
    const int tr = tid >> 4;
    const int tc = tid & 15;
    const int gBase = blockIdx.x * 64;
    const int cBase = blockIdx.y * 64;

    float acc[4][4];
#pragma unroll
    for (int i = 0; i < 4; ++i)
#pragma unroll
        for (int j = 0; j < 4; ++j) acc[i][j] = 0.f;

    for (int kb = 0; kb < 640; kb += 64) {
#pragma unroll
        for (int i = 0; i < 4; ++i) {
            int f4 = tid + i * 256;
            int r  = f4 >> 4;
            int kc = (f4 & 15) << 2;
            int gg = gBase + r;
            float4 v = {0.f, 0.f, 0.f, 0.f};
            if (gg < G) v = *(const float4*)(P + (size_t)gg * 640 + kb + kc);
            As[kc + 0][r] = v.x; As[kc + 1][r] = v.y;
            As[kc + 2][r] = v.z; As[kc + 3][r] = v.w;
        }
#pragma unroll
        for (int i = 0; i < 4; ++i) {
            int f4 = tid + i * 256;
            int k  = f4 >> 4;
            int c4 = (f4 & 15) << 2;
            *(float4*)&Ws[k][c4] =
                *(const float4*)(Wl1 + (size_t)(kb + k) * 640 + cBase + c4);
        }
        __syncthreads();
#pragma unroll
        for (int k = 0; k < 64; ++k) {
            float a[4], w[4];
            *(float4*)&a[0] = *(const float4*)&As[k][tr * 4];
            *(float4*)&w[0] = *(const float4*)&Ws[k][tc * 4];
#pragma unroll
            for (int i = 0; i < 4; ++i)
#pragma unroll
                for (int j = 0; j < 4; ++j)
                    acc[i][j] = fmaf(a[i], w[j], acc[i][j]);
        }
        __syncthreads();
    }
#pragma unroll
    for (int i = 0; i < 4; ++i) {
        int gg = gBase + tr * 4 + i;
        if (gg < G) {
            float4 o;
            o.x = fmaxf(acc[i][0] + bl1[cBase + tc * 4 + 0], 0.f);
            o.y = fmaxf(acc[i][1] + bl1[cBase + tc * 4 + 1], 0.f);
            o.z = fmaxf(acc[i][2] + bl1[cBase + tc * 4 + 2], 0.f);
            o.w = fmaxf(acc[i][3] + bl1[cBase + tc * 4 + 3], 0.f);
            *(float4*)(Z + (size_t)gg * 640 + cBase + tc * 4) = o;
        }
    }
}

__global__ void k_fc2(const float* __restrict__ zbuf, const float* __restrict__ Wl2,
                      const float* __restrict__ bl2, float* __restrict__ out) {
    int g = blockIdx.x;
    int t = threadIdx.x;  // 128 threads = 2 waves
    float s = 0.f;
    for (int k = t; k < 640; k += 128) s = fmaf(zbuf[(size_t)g * 640 + k], Wl2[k], s);
#pragma unroll
    for (int off = 32; off > 0; off >>= 1) s += __shfl_down(s, off);
    __shared__ float ws[2];
    if ((t & 63) == 0) ws[t >> 6] = s;
    __syncthreads();
    if (t == 0) out[g] = ws[0] + ws[1] + bl2[0];
}

// ---------------- driver ----------------
extern "C" void kernel_launch(void* const* d_in, const int* in_sizes, int n_in,
                              void* d_out, int out_size, void* d_ws, size_t ws_size,
                              hipStream_t stream) {
    const float* x    = (const float*)d_in[0];
    const int*   edge = (const int*)d_in[1];
    const int*   bat  = (const int*)d_in[2];
    const float* W1   = (const float*)d_in[3];
    const float* b1   = (const float*)d_in[4];
    const float* W2   = (const float*)d_in[5];
    const float* b2   = (const float*)d_in[6];
    const float* W3   = (const float*)d_in[7];
    const float* b3   = (const float*)d_in[8];
    const float* W4   = (const float*)d_in[9];
    const float* b4   = (const float*)d_in[10];
    const float* Wl1  = (const float*)d_in[11];
    const float* bl1  = (const float*)d_in[12];
    const float* Wl2  = (const float*)d_in[13];
    const float* bl2  = (const float*)d_in[14];
    float*       out  = (float*)d_out;

    const int N = in_sizes[2];       // 100000
    const int E = in_sizes[1] / 2;   // 1600000
    const int G = out_size;          // 512
    (void)n_in; (void)ws_size;

    (void)hipGetLastError();  // clear any stale error

    // ---- workspace carve ----
    size_t off = 0;
    auto alloc = [&](size_t bytes) -> void* {
        void* p = (void*)((char*)d_ws + off);
        off += (bytes + 255) & ~(size_t)255;
        return p;
    };
    unsigned short* buf0 = (unsigned short*)alloc((size_t)N * HID * 2);  // t, bf16
    unsigned short* buf1 = (unsigned short*)alloc((size_t)N * HID * 2);  // h, bf16
    float* dinv   = (float*)alloc((size_t)N * 4);
    int*   degI   = (int*)alloc((size_t)N * 4);
    int*   cursor = (int*)alloc((size_t)N * 4);
    int*   indptr = (int*)alloc((size_t)(N + 1) * 4);
    int*   partial= (int*)alloc((size_t)N * 4);
    int*   bsums  = (int*)alloc((size_t)1024 * 4);
    int2*  adj    = (int2*)alloc((size_t)(E + N) * 8);
    int*   cntG   = (int*)alloc((size_t)G * 4);
    int*   gstart = (int*)alloc((size_t)(G + 1) * 4);
    float* pbuf   = (float*)alloc((size_t)G * 640 * 4);
    float* zbuf   = (float*)alloc((size_t)G * 640 * 4);

    const int* rowv = edge;      // sources
    const int* colv = edge + E;  // destinations

    // ---- preprocessing (once, reused by all 5 convs) ----
    hipMemsetAsync(degI, 0, (size_t)N * 4, stream);
    hipMemsetAsync(cntG, 0, (size_t)G * 4, stream);
    k_deg<<<(E + 255) / 256, 256, 0, stream>>>(colv, degI, E);
    k_dinv<<<(N + 255) / 256, 256, 0, stream>>>(degI, dinv, N);
    const int scanBlocks = (N + 1023) / 1024;
    k_scan_part<<<scanBlocks, 1024, 0, stream>>>(degI, partial, bsums, N);
    k_scan_tops<<<1, 1024, 0, stream>>>(bsums, indptr, scanBlocks, N);
    k_scan_fix<<<(N + 255) / 256, 256, 0, stream>>>(partial, bsums, indptr, cursor, N);
    const int S = 128;   // edge slices per dest-range group (grid = 8*S)
    k_scatter<<<8 * S, 256, 0, stream>>>(rowv, colv, dinv, cursor, adj, E, N, S);
    k_ghist<<<(N + 255) / 256, 256, 0, stream>>>(bat, cntG, N);
    k_gscan<<<1, 512, 0, stream>>>(cntG, gstart, G);

    // ---- 5 GCN layers (layer 5 reuses W4/b4, matching the reference) ----
    const float* Ws_[5] = {W1, W2, W3, W4, W4};
    const float* bs_[5] = {b1, b2, b3, b4, b4};
    const int gemmGrid = (N + 127) / 128;
    const int aggGrid  = (N + 3) / 4;
    const int poolGrid = (G + 3) / 4;
    for (int L = 0; L < 5; ++L) {
        if (L == 0)
            k_gemm_mfma<float><<<gemmGrid, 256, 0, stream>>>(x, Ws_[0], buf0, N);
        else
            k_gemm_mfma<unsigned short><<<gemmGrid, 256, 0, stream>>>(buf1, Ws_[L], buf0, N);
        k_aggregate<<<aggGrid, 256, 0, stream>>>(buf0, indptr, adj, bs_[L], buf1, N);
        k_pool<<<poolGrid, 256, 0, stream>>>(buf1, gstart, cntG, pbuf, L, G);
    }

    // ---- MLP head ----
    dim3 hgrid((G + 63) / 64, 10);   // 640 output cols / 64
    k_head1<<<hgrid, 256, 0, stream>>>(pbuf, Wl1, bl1, zbuf, G);
    k_fc2<<<G, 128, 0, stream>>>(zbuf, Wl2, bl2, out);

    // sentinel: some launch failed synchronously (absmax ~= 48)
    if (hipGetLastError() != hipSuccess)
        hipMemsetAsync(d_out, 0x42, (size_t)out_size * 4, stream);
}

// Round 9
// 870.638 us; speedup vs baseline: 2.4483x; 1.1215x over previous
//
#include <hip/hip_runtime.h>

#define HID 128   // feature width (D == H == 128)

// ---------------- bf16 helpers ----------------
__device__ __forceinline__ float bf2f(unsigned short u) {
    union { unsigned int i; float f; } v;
    v.i = ((unsigned int)u) << 16;
    return v.f;
}
__device__ __forceinline__ unsigned short f2bf(float f) {
    union { float f; unsigned int i; } v;
    v.f = f;
    unsigned int lsb = (v.i >> 16) & 1u;
    v.i += 0x7fffu + lsb;   // round-to-nearest-even
    return (unsigned short)(v.i >> 16);
}

typedef __attribute__((ext_vector_type(8))) short bf16x8;   // 8 bf16 (4 VGPRs)
typedef __attribute__((ext_vector_type(4))) float f32x4;    // MFMA acc

// ---------------- preprocessing ----------------
__global__ void k_deg(const int* __restrict__ col, int* __restrict__ degI, int E) {
    int i = blockIdx.x * blockDim.x + threadIdx.x;
    if (i < E) atomicAdd(&degI[col[i]], 1);
}

// ---- 3-phase device-wide exclusive scan of (degI[i]+1) -> indptr, cursor ----
__global__ void k_scan_part(const int* __restrict__ degI, int* __restrict__ partial,
                            int* __restrict__ sums, int N) {
    __shared__ int sh[1024];
    int tid = threadIdx.x;
    int i = blockIdx.x * 1024 + tid;
    int v = (i < N) ? (degI[i] + 1) : 0;
    sh[tid] = v;
    __syncthreads();
    for (int off = 1; off < 1024; off <<= 1) {
        int t = (tid >= off) ? sh[tid - off] : 0;
        __syncthreads();
        sh[tid] += t;
        __syncthreads();
    }
    if (i < N) partial[i] = sh[tid] - v;
    if (tid == 1023) sums[blockIdx.x] = sh[1023];
}
__global__ void k_scan_tops(int* __restrict__ sums, int* __restrict__ indptr,
                            int nblocks, int N) {
    __shared__ int sh[1024];
    int tid = threadIdx.x;
    int v = (tid < nblocks) ? sums[tid] : 0;
    sh[tid] = v;
    __syncthreads();
    for (int off = 1; off < 1024; off <<= 1) {
        int t = (tid >= off) ? sh[tid - off] : 0;
        __syncthreads();
        sh[tid] += t;
        __syncthreads();
    }
    if (tid < nblocks) sums[tid] = sh[tid] - v;   // exclusive
    if (tid == 1023) indptr[N] = sh[1023];        // grand total = E + N
}
// phase 3: emit indptr + cursor, and fold in dinv = 1/sqrt(deg+1)
__global__ void k_scan_fix(const int* __restrict__ partial, const int* __restrict__ sums,
                           const int* __restrict__ degI, int* __restrict__ indptr,
                           int* __restrict__ cursor, float* __restrict__ dinv, int N) {
    int i = blockIdx.x * blockDim.x + threadIdx.x;
    if (i < N) {
        int ex = partial[i] + sums[i >> 10];
        indptr[i] = ex;
        cursor[i] = ex;
        dinv[i] = 1.0f / sqrtf((float)(degI[i] + 1));
    }
}

// batch is SORTED -> graph segment bounds via binary search (replaces the
// same-address-atomic histogram which serialized at 85us).
__global__ void k_gbounds(const int* __restrict__ batch, int* __restrict__ gstart,
                          int N, int G) {
    int g = blockIdx.x * blockDim.x + threadIdx.x;
    if (g > G) return;
    int lo = 0, hi = N;
    while (lo < hi) {
        int mid = (lo + hi) >> 1;
        if (batch[mid] < g) lo = mid + 1; else hi = mid;
    }
    gstart[g] = lo;   // lower_bound: first node with batch >= g
}

// ---------------- fat kernel: layer-0 MFMA GEMM + flat CSR scatter -----------
// gemm0 (x@W1 -> buf0) and the CSR build are independent; fusing them overlaps
// the scatter's memory-side line-RMW traffic with gemm0's MFMA compute.
// Blocks [0, gemmGrid) do GEMM; blocks [gemmGrid, gemmGrid+scatGrid) scatter.
__device__ __forceinline__ bf16x8 a_frag_load(const unsigned short* p) {
    return *(const bf16x8*)p;
}
__device__ __forceinline__ bf16x8 a_frag_load(const float* p) {
    bf16x8 r;
#pragma unroll
    for (int i = 0; i < 8; ++i) r[i] = (short)f2bf(p[i]);
    return r;
}

template <typename TA>
__device__ __forceinline__ void gemm_body(const TA* __restrict__ A,
                                          const float* __restrict__ W,
                                          unsigned short* __restrict__ C,
                                          int N, int blk,
                                          unsigned short* Wsw) {
    const int tid = threadIdx.x;
    for (int i = tid; i < 16384; i += 256) {
        int k = i >> 7, n = i & 127;
        int ks = k >> 5, q = (k >> 3) & 3, j = k & 7;
        int ct = n >> 4, c = n & 15;
        Wsw[((((ks * 8 + ct) * 4 + q) * 16 + c) << 3) + j] = f2bf(W[i]);
    }
    __syncthreads();

    const int lane = tid & 63, wave = tid >> 6;
    const int q = lane >> 4, c = lane & 15;
    const int rowBase = blk * 128 + wave * 32;

    f32x4 acc[2][8];
#pragma unroll
    for (int rt = 0; rt < 2; ++rt)
#pragma unroll
        for (int ct = 0; ct < 8; ++ct)
            acc[rt][ct] = (f32x4){0.f, 0.f, 0.f, 0.f};

    const bf16x8 zfrag = {};
#pragma unroll
    for (int ks = 0; ks < 4; ++ks) {
        bf16x8 a[2];
#pragma unroll
        for (int rt = 0; rt < 2; ++rt) {
            int r = rowBase + rt * 16 + c;
            a[rt] = (r < N) ? a_frag_load(A + (size_t)r * HID + ks * 32 + q * 8)
                            : zfrag;
        }
#pragma unroll
        for (int ct = 0; ct < 8; ++ct) {
            bf16x8 b = *(const bf16x8*)&Wsw[((((ks * 8 + ct) * 4 + q) * 16 + c) << 3)];
            acc[0][ct] = __builtin_amdgcn_mfma_f32_16x16x32_bf16(a[0], b, acc[0][ct], 0, 0, 0);
            acc[1][ct] = __builtin_amdgcn_mfma_f32_16x16x32_bf16(a[1], b, acc[1][ct], 0, 0, 0);
        }
    }
#pragma unroll
    for (int rt = 0; rt < 2; ++rt)
#pragma unroll
        for (int reg = 0; reg < 4; ++reg) {
            int r = rowBase + rt * 16 + q * 4 + reg;
            if (r < N) {
#pragma unroll
                for (int ct = 0; ct < 8; ++ct)
                    C[(size_t)r * HID + ct * 16 + c] = f2bf(acc[rt][ct][reg]);
            }
        }
}

__global__ __launch_bounds__(256) void k_fused0(const float* __restrict__ x,
                                                const float* __restrict__ W1,
                                                unsigned short* __restrict__ buf0,
                                                const int* __restrict__ row,
                                                const int* __restrict__ col,
                                                const float* __restrict__ dinv,
                                                int* __restrict__ cursor,
                                                int2* __restrict__ adj,
                                                int E, int N, int gemmGrid) {
    __shared__ unsigned short Wsw[16384];   // 32 KB (gemm path only)
    if (blockIdx.x < gemmGrid) {
        gemm_body<float>(x, W1, buf0, N, blockIdx.x, Wsw);
        return;
    }
    int e = (blockIdx.x - gemmGrid) * blockDim.x + threadIdx.x;
    if (e >= E + N) return;
    int s, d;
    if (e < E) { s = row[e]; d = col[e]; }
    else       { s = d = e - E; }          // self loop
    int p = atomicAdd(&cursor[d], 1);
    adj[p] = make_int2(s, __float_as_int(dinv[s] * dinv[d]));
}

// layers 1..4 GEMM (A is bf16)
__global__ __launch_bounds__(256) void k_gemm_mfma(const unsigned short* __restrict__ A,
                                                   const float* __restrict__ W,
                                                   unsigned short* __restrict__ C,
                                                   int N) {
    __shared__ unsigned short Wsw[16384];
    gemm_body<unsigned short>(A, W, C, N, blockIdx.x, Wsw);
}

// ---------------- CSR gather-aggregate + bias + ReLU ----------------
__global__ __launch_bounds__(256) void k_aggregate(const unsigned short* __restrict__ t,
                                                   const int* __restrict__ indptr,
                                                   const int2* __restrict__ adj,
                                                   const float* __restrict__ bias,
                                                   unsigned short* __restrict__ h, int N) {
    int node = blockIdx.x * 4 + (threadIdx.x >> 6);
    if (node >= N) return;
    int lane = threadIdx.x & 63;
    int s = indptr[node], e = indptr[node + 1];
    float ax[4] = {0.f, 0.f, 0.f, 0.f};
    float ay[4] = {0.f, 0.f, 0.f, 0.f};
    int p = s;
    for (; p + 7 < e; p += 8) {
        unsigned int v[8];
        float w[8];
#pragma unroll
        for (int u = 0; u < 8; ++u) {
            int2 ae = adj[p + u];
            w[u] = __int_as_float(ae.y);
            v[u] = ((const unsigned int*)(t + (size_t)ae.x * HID))[lane];
        }
#pragma unroll
        for (int u = 0; u < 8; ++u) {
            float lo = bf2f((unsigned short)(v[u] & 0xffffu));
            float hi = bf2f((unsigned short)(v[u] >> 16));
            ax[u & 3] = fmaf(w[u], lo, ax[u & 3]);
            ay[u & 3] = fmaf(w[u], hi, ay[u & 3]);
        }
    }
    for (; p < e; ++p) {
        int2 ae = adj[p];
        float ww = __int_as_float(ae.y);
        unsigned int v = ((const unsigned int*)(t + (size_t)ae.x * HID))[lane];
        ax[0] = fmaf(ww, bf2f((unsigned short)(v & 0xffffu)), ax[0]);
        ay[0] = fmaf(ww, bf2f((unsigned short)(v >> 16)), ay[0]);
    }
    float ox = fmaxf((ax[0] + ax[1]) + (ax[2] + ax[3]) + bias[lane * 2], 0.f);
    float oy = fmaxf((ay[0] + ay[1]) + (ay[2] + ay[3]) + bias[lane * 2 + 1], 0.f);
    unsigned int pk = (unsigned int)f2bf(ox) | ((unsigned int)f2bf(oy) << 16);
    ((unsigned int*)(h + (size_t)node * HID))[lane] = pk;
}

// ---------------- segment mean-pool: one wave per graph, 8-deep unroll -------
__global__ __launch_bounds__(256) void k_pool(const unsigned short* __restrict__ h,
                                              const int* __restrict__ gstart,
                                              float* __restrict__ pbuf,
                                              int layer, int G) {
    int g = blockIdx.x * 4 + (threadIdx.x >> 6);
    if (g >= G) return;
    int lane = threadIdx.x & 63;
    int s = gstart[g], e = gstart[g + 1];
    float sx[4] = {0.f, 0.f, 0.f, 0.f};
    float sy[4] = {0.f, 0.f, 0.f, 0.f};
    int v = s;
    for (; v + 7 < e; v += 8) {
        unsigned int pk[8];
#pragma unroll
        for (int u = 0; u < 8; ++u)
            pk[u] = ((const unsigned int*)(h + (size_t)(v + u) * HID))[lane];
#pragma unroll
        for (int u = 0; u < 8; ++u) {
            sx[u & 3] += bf2f((unsigned short)(pk[u] & 0xffffu));
            sy[u & 3] += bf2f((unsigned short)(pk[u] >> 16));
        }
    }
    for (; v < e; ++v) {
        unsigned int pk = ((const unsigned int*)(h + (size_t)v * HID))[lane];
        sx[0] += bf2f((unsigned short)(pk & 0xffffu));
        sy[0] += bf2f((unsigned short)(pk >> 16));
    }
    float inv = 1.0f / fmaxf((float)(e - s), 1.0f);
    float ox = ((sx[0] + sx[1]) + (sx[2] + sx[3])) * inv;
    float oy = ((sy[0] + sy[1]) + (sy[2] + sy[3])) * inv;
    float* dst = pbuf + (size_t)g * 640 + layer * HID + lane * 2;
    dst[0] = ox;
    dst[1] = oy;
}

// ---------------- MLP head: Z[G,640] = relu(P[G,640] @ Wl1 + bl1) ------------
__global__ __launch_bounds__(256) void k_head1(const float* __restrict__ P,
                                               const float* __restrict__ Wl1,
                                               const float* __restrict__ bl1,
                                               float* __restrict__ Z, int G) {
    __shared__ float As[64][68];
    __shared__ float Ws[64][64];
    const int tid = threadIdx.x;
    const int tr = tid >> 4;
    const int tc = tid & 15;
    const int gBase = blockIdx.x * 64;
    const int cBase = blockIdx.y * 64;

    float acc[4][4];
#pragma unroll
    for (int i = 0; i < 4; ++i)
#pragma unroll
        for (int j = 0; j < 4; ++j) acc[i][j] = 0.f;

    for (int kb = 0; kb < 640; kb += 64) {
#pragma unroll
        for (int i = 0; i < 4; ++i) {
            int f4 = tid + i * 256;
            int r  = f4 >> 4;
            int kc = (f4 & 15) << 2;
            int gg = gBase + r;
            float4 v = {0.f, 0.f, 0.f, 0.f};
            if (gg < G) v = *(const float4*)(P + (size_t)gg * 640 + kb + kc);
            As[kc + 0][r] = v.x; As[kc + 1][r] = v.y;
            As[kc + 2][r] = v.z; As[kc + 3][r] = v.w;
        }
#pragma unroll
        for (int i = 0; i < 4; ++i) {
            int f4 = tid + i * 256;
            int k  = f4 >> 4;
            int c4 = (f4 & 15) << 2;
            *(float4*)&Ws[k][c4] =
                *(const float4*)(Wl1 + (size_t)(kb + k) * 640 + cBase + c4);
        }
        __syncthreads();
#pragma unroll
        for (int k = 0; k < 64; ++k) {
            float a[4], w[4];
            *(float4*)&a[0] = *(const float4*)&As[k][tr * 4];
            *(float4*)&w[0] = *(const float4*)&Ws[k][tc * 4];
#pragma unroll
            for (int i = 0; i < 4; ++i)
#pragma unroll
                for (int j = 0; j < 4; ++j)
                    acc[i][j] = fmaf(a[i], w[j], acc[i][j]);
        }
        __syncthreads();
    }
#pragma unroll
    for (int i = 0; i < 4; ++i) {
        int gg = gBase + tr * 4 + i;
        if (gg < G) {
            float4 o;
            o.x = fmaxf(acc[i][0] + bl1[cBase + tc * 4 + 0], 0.f);
            o.y = fmaxf(acc[i][1] + bl1[cBase + tc * 4 + 1], 0.f);
            o.z = fmaxf(acc[i][2] + bl1[cBase + tc * 4 + 2], 0.f);
            o.w = fmaxf(acc[i][3] + bl1[cBase + tc * 4 + 3], 0.f);
            *(float4*)(Z + (size_t)gg * 640 + cBase + tc * 4) = o;
        }
    }
}

__global__ void k_fc2(const float* __restrict__ zbuf, const float* __restrict__ Wl2,
                      const float* __restrict__ bl2, float* __restrict__ out) {
    int g = blockIdx.x;
    int t = threadIdx.x;  // 128 threads = 2 waves
    float s = 0.f;
    for (int k = t; k < 640; k += 128) s = fmaf(zbuf[(size_t)g * 640 + k], Wl2[k], s);
#pragma unroll
    for (int off = 32; off > 0; off >>= 1) s += __shfl_down(s, off);
    __shared__ float ws[2];
    if ((t & 63) == 0) ws[t >> 6] = s;
    __syncthreads();
    if (t == 0) out[g] = ws[0] + ws[1] + bl2[0];
}

// ---------------- driver ----------------
extern "C" void kernel_launch(void* const* d_in, const int* in_sizes, int n_in,
                              void* d_out, int out_size, void* d_ws, size_t ws_size,
                              hipStream_t stream) {
    const float* x    = (const float*)d_in[0];
    const int*   edge = (const int*)d_in[1];
    const int*   bat  = (const int*)d_in[2];
    const float* W1   = (const float*)d_in[3];
    const float* b1   = (const float*)d_in[4];
    const float* W2   = (const float*)d_in[5];
    const float* b2   = (const float*)d_in[6];
    const float* W3   = (const float*)d_in[7];
    const float* b3   = (const float*)d_in[8];
    const float* W4   = (const float*)d_in[9];
    const float* b4   = (const float*)d_in[10];
    const float* Wl1  = (const float*)d_in[11];
    const float* bl1  = (const float*)d_in[12];
    const float* Wl2  = (const float*)d_in[13];
    const float* bl2  = (const float*)d_in[14];
    float*       out  = (float*)d_out;

    const int N = in_sizes[2];       // 100000
    const int E = in_sizes[1] / 2;   // 1600000
    const int G = out_size;          // 512
    (void)n_in; (void)ws_size;

    (void)hipGetLastError();  // clear any stale error

    // ---- workspace carve ----
    size_t off = 0;
    auto alloc = [&](size_t bytes) -> void* {
        void* p = (void*)((char*)d_ws + off);
        off += (bytes + 255) & ~(size_t)255;
        return p;
    };
    unsigned short* buf0 = (unsigned short*)alloc((size_t)N * HID * 2);  // t, bf16
    unsigned short* buf1 = (unsigned short*)alloc((size_t)N * HID * 2);  // h, bf16
    float* dinv   = (float*)alloc((size_t)N * 4);
    int*   degI   = (int*)alloc((size_t)N * 4);
    int*   cursor = (int*)alloc((size_t)N * 4);
    int*   indptr = (int*)alloc((size_t)(N + 1) * 4);
    int*   partial= (int*)alloc((size_t)N * 4);
    int*   bsums  = (int*)alloc((size_t)1024 * 4);
    int2*  adj    = (int2*)alloc((size_t)(E + N) * 8);
    int*   gstart = (int*)alloc((size_t)(G + 1) * 4);
    float* pbuf   = (float*)alloc((size_t)G * 640 * 4);
    float* zbuf   = (float*)alloc((size_t)G * 640 * 4);

    const int* rowv = edge;      // sources
    const int* colv = edge + E;  // destinations

    // ---- preprocessing ----
    hipMemsetAsync(degI, 0, (size_t)N * 4, stream);
    k_deg<<<(E + 255) / 256, 256, 0, stream>>>(colv, degI, E);
    const int scanBlocks = (N + 1023) / 1024;
    k_scan_part<<<scanBlocks, 1024, 0, stream>>>(degI, partial, bsums, N);
    k_scan_tops<<<1, 1024, 0, stream>>>(bsums, indptr, scanBlocks, N);
    k_scan_fix<<<(N + 255) / 256, 256, 0, stream>>>(partial, bsums, degI,
                                                    indptr, cursor, dinv, N);
    k_gbounds<<<(G + 256) / 256, 256, 0, stream>>>(bat, gstart, N, G);

    // ---- fused: layer-0 GEMM + CSR scatter (independent; overlap) ----
    const int gemmGrid = (N + 127) / 128;
    const int scatGrid = (E + N + 255) / 256;
    k_fused0<<<gemmGrid + scatGrid, 256, 0, stream>>>(x, W1, buf0, rowv, colv,
                                                      dinv, cursor, adj,
                                                      E, N, gemmGrid);

    // ---- 5 GCN layers (layer 5 reuses W4/b4, matching the reference) ----
    const float* bs_[5] = {b1, b2, b3, b4, b4};
    const float* Ws_[5] = {W1, W2, W3, W4, W4};
    const int aggGrid  = (N + 3) / 4;
    const int poolGrid = (G + 3) / 4;
    for (int L = 0; L < 5; ++L) {
        if (L > 0)
            k_gemm_mfma<<<gemmGrid, 256, 0, stream>>>(buf1, Ws_[L], buf0, N);
        k_aggregate<<<aggGrid, 256, 0, stream>>>(buf0, indptr, adj, bs_[L], buf1, N);
        k_pool<<<poolGrid, 256, 0, stream>>>(buf1, gstart, pbuf, L, G);
    }

    // ---- MLP head ----
    dim3 hgrid((G + 63) / 64, 10);   // 640 output cols / 64
    k_head1<<<hgrid, 256, 0, stream>>>(pbuf, Wl1, bl1, zbuf, G);
    k_fc2<<<G, 128, 0, stream>>>(zbuf, Wl2, bl2, out);

    // sentinel: some launch failed synchronously (absmax ~= 48)
    if (hipGetLastError() != hipSuccess)
        hipMemsetAsync(d_out, 0x42, (size_t)out_size * 4, stream);
}